// Round 18
// baseline (218.534 us; speedup 1.0000x reference)
//
#include <hip/hip_runtime.h>
#include <stdint.h>

#define DI __device__ __forceinline__

typedef __attribute__((ext_vector_type(8))) short bfx8;
typedef __attribute__((ext_vector_type(4))) short bfx4;
typedef __attribute__((ext_vector_type(4))) float f4;

DI unsigned short f2bf(float x){
  unsigned u = __float_as_uint(x);
  u = (u + 0x7FFFu + ((u >> 16) & 1u)) >> 16;
  return (unsigned short)u;
}
DI float bf2f(unsigned short h){ return __uint_as_float(((unsigned)h) << 16); }

// packed RNE f32->bf16x2 (same rounding as f2bf)
DI unsigned cvtpk(float lo, float hi){
  unsigned r;
  asm("v_cvt_pk_bf16_f32 %0, %1, %2" : "=v"(r) : "v"(lo), "v"(hi));
  return r;
}

DI f4 mfma32(bfx8 a, bfx8 b, f4 c){
  return __builtin_amdgcn_mfma_f32_16x16x32_bf16(a, b, c, 0, 0, 0);
}
#if __has_builtin(__builtin_amdgcn_mfma_f32_16x16x16bf16_1k)
DI f4 mfma16(bfx4 a, bfx4 b, f4 c){
  return __builtin_amdgcn_mfma_f32_16x16x16bf16_1k(a, b, c, 0, 0, 0);
}
#else
DI f4 mfma16(bfx4 a, bfx4 b, f4 c){
  f4 d = c;
  asm volatile("v_mfma_f32_16x16x16_bf16 %0, %1, %2, %0" : "+v"(d) : "v"(a), "v"(b));
  return d;
}
#endif

DI bfx4 lo4(bfx8 v){ bfx4 r; r[0]=v[0]; r[1]=v[1]; r[2]=v[2]; r[3]=v[3]; return r; }
DI bfx4 hi4(bfx8 v){ bfx4 r; r[0]=v[4]; r[1]=v[5]; r[2]=v[6]; r[3]=v[7]; return r; }

// async global->LDS, 16B per lane; LDS dest = wave-uniform base + lane*16
DI void gload16(const void* g, void* l){
  __builtin_amdgcn_global_load_lds(
      (__attribute__((address_space(1))) void*)g,
      (__attribute__((address_space(3))) void*)l, 16, 0, 0);
}

// Fragment layouts (all 16-bit elems):
//   Qf/Kf[bh][tile][lane][16]: elem[kf*8+j] = M[tile*16 + (lane&15)][kf*32 + 8*(lane>>4) + j]
//   Vf  [bh][tile][lane][16]: elem[df*4+j] = V[tile*16 + 4*(lane>>4) + j][df*16 + (lane&15)]
//   ivf [b][tt][st][lane][4]: elem[r] = 1/S at (s = st*16 + (lane&15), t = tt*16 + 4*(lane>>4) + r)

// ---------------- merged prep: x cast | 4 weight casts | rel tables ----------------
__global__ void k_prep(const float* __restrict__ x,
                       const float* __restrict__ wq, const float* __restrict__ wk,
                       const float* __restrict__ wv, const float* __restrict__ wo,
                       const float* __restrict__ rlk, const float* __restrict__ rlv,
                       unsigned short* __restrict__ x_bf, unsigned short* __restrict__ w_bf,
                       unsigned short* __restrict__ relk_bf, unsigned short* __restrict__ relvT_bf){
  const int bid = blockIdx.x;
  if (bid < 4096){
    int i = bid*256 + threadIdx.x;
    const float4 v = ((const float4*)x)[i];
    bfx4 o;
    o[0] = (short)f2bf(v.x); o[1] = (short)f2bf(v.y);
    o[2] = (short)f2bf(v.z); o[3] = (short)f2bf(v.w);
    *(bfx4*)(x_bf + (size_t)i*4) = o;
  } else if (bid < 8192){
    const int wb = (bid - 4096) >> 10;
    const float* src = (wb==0) ? wq : (wb==1) ? wk : (wb==2) ? wv : wo;
    int i = ((bid - 4096) & 1023)*256 + threadIdx.x;
    const float4 v = ((const float4*)src)[i];
    bfx4 o;
    o[0] = (short)f2bf(v.x); o[1] = (short)f2bf(v.y);
    o[2] = (short)f2bf(v.z); o[3] = (short)f2bf(v.w);
    *(bfx4*)(w_bf + (size_t)wb*1048576 + (size_t)i*4) = o;
  } else {
    int i = (bid - 8192)*256 + threadIdx.x;
    if (i < 272*64){
      int r = i >> 6, d = i & 63;
      relk_bf[i] = (r < 257) ? f2bf(rlk[r*64 + d]) : (unsigned short)0;
    }
    if (i < 64*288){
      int d = i / 288, r = i % 288;
      relvT_bf[i] = (r < 257) ? f2bf(rlv[(size_t)r*64 + d]) : (unsigned short)0;
    }
  }
}

// ---------------- QKV projections: counted-vmcnt double-buffered pipeline ----------------
__global__ __launch_bounds__(256, 4) void k_qkv(
    const unsigned short* __restrict__ xbf, const unsigned short* __restrict__ wqkv,
    unsigned short* __restrict__ Qf, unsigned short* __restrict__ Kf,
    unsigned short* __restrict__ Vf)
{
  __shared__ __align__(16) unsigned short smem[2][8192];   // 2 x 16 KB: A blocks 0-7, B blocks 8-15
  const int nt = blockIdx.x;
  const int b  = blockIdx.y;
  const int st = blockIdx.z;
  const int w = threadIdx.x >> 6, lane = threadIdx.x & 63;
  const int wr = w >> 1, wc = w & 1;
  const int p = lane & 15, g = lane >> 4;
  const int s0 = st*128;
  const int n0 = nt*128;
  const f4 fz = {0.f,0.f,0.f,0.f};
  f4 acc[4][4];
#pragma unroll
  for (int m=0;m<4;++m)
#pragma unroll
    for (int n=0;n<4;++n) acc[m][n] = fz;

  const int j0 = w*2, j1 = w*2 + 1;
  const unsigned short* gA = xbf  + (size_t)((s0 + p)*4 + b)*1024 + g*8;
  const unsigned short* gB = wqkv + (size_t)(n0 + p)*1024 + g*8;

  {
    unsigned short* d0 = &smem[0][0];
    gload16(gA + (size_t)j0*65536, d0 + j0*512);
    gload16(gA + (size_t)j1*65536, d0 + j1*512);
    gload16(gB + (size_t)j0*16384, d0 + 4096 + j0*512);
    gload16(gB + (size_t)j1*16384, d0 + 4096 + j1*512);
  }

  for (int it=0; it<32; ++it){
    const int cur = it & 1;
    if (it < 31){
      const int kn = (it+1)*32;
      unsigned short* dn = &smem[cur^1][0];
      gload16(gA + (size_t)j0*65536 + kn, dn + j0*512);
      gload16(gA + (size_t)j1*65536 + kn, dn + j1*512);
      gload16(gB + (size_t)j0*16384 + kn, dn + 4096 + j0*512);
      gload16(gB + (size_t)j1*16384 + kn, dn + 4096 + j1*512);
      asm volatile("s_waitcnt vmcnt(4)" ::: "memory");
    } else {
      asm volatile("s_waitcnt vmcnt(0)" ::: "memory");
    }
    __builtin_amdgcn_sched_barrier(0);
    __builtin_amdgcn_s_barrier();
    __builtin_amdgcn_sched_barrier(0);
    {
      const unsigned short* Ab = &smem[cur][0];
      bfx8 af[4], bfr[4];
#pragma unroll
      for (int m=0;m<4;++m) af[m] = *(const bfx8*)(Ab + (wr*4+m)*512 + lane*8);
#pragma unroll
      for (int n=0;n<4;++n) bfr[n] = *(const bfx8*)(Ab + 4096 + (wc*4+n)*512 + lane*8);
#pragma unroll
      for (int m=0;m<4;++m)
#pragma unroll
        for (int n=0;n<4;++n)
          acc[m][n] = mfma32(af[m], bfr[n], acc[m][n]);
    }
    __builtin_amdgcn_sched_barrier(0);
    __builtin_amdgcn_s_barrier();
    __builtin_amdgcn_sched_barrier(0);
  }

  const int n64 = n0 + wc*64;
  const int sec = n64 >> 10;            // 0 Q, 1 K, 2 V
  const int h = (n64 & 1023) >> 6;
  float* es = (float*)&smem[0][0] + w*1280;

  if (sec < 2){
    const float scl = (sec == 0) ? 0.125f : 1.0f;
    unsigned short* dst = (sec == 0) ? Qf : Kf;
#pragma unroll
    for (int m=0;m<4;++m){
#pragma unroll
      for (int n=0;n<4;++n)
#pragma unroll
        for (int r=0;r<4;++r)
          es[(4*g + r)*80 + 16*n + p] = acc[m][n][r] * scl;
      __syncthreads();
      f4 v0 = *(const f4*)&es[p*80 + 8*g];
      f4 v1 = *(const f4*)&es[p*80 + 8*g + 4];
      f4 v2 = *(const f4*)&es[p*80 + 32 + 8*g];
      f4 v3 = *(const f4*)&es[p*80 + 32 + 8*g + 4];
      bfx8 lo, hi;
#pragma unroll
      for (int j=0;j<4;++j){
        lo[j]   = (short)f2bf(v0[j]);
        lo[j+4] = (short)f2bf(v1[j]);
        hi[j]   = (short)f2bf(v2[j]);
        hi[j+4] = (short)f2bf(v3[j]);
      }
      size_t fb = ((size_t)(b*16 + h)*64 + (st*8 + wr*4 + m))*1024 + (size_t)lane*16;
      *(bfx8*)(dst + fb) = lo;
      *(bfx8*)(dst + fb + 8) = hi;
      __syncthreads();
    }
  } else {
#pragma unroll
    for (int m=0;m<4;++m){
#pragma unroll
      for (int n=0;n<4;++n)
        *(f4*)&es[(16*n + p)*20 + 4*g] = acc[m][n];
      __syncthreads();
      f4 vv0 = *(const f4*)&es[(p)*20 + 4*g];
      f4 vv1 = *(const f4*)&es[(16 + p)*20 + 4*g];
      f4 vv2 = *(const f4*)&es[(32 + p)*20 + 4*g];
      f4 vv3 = *(const f4*)&es[(48 + p)*20 + 4*g];
      bfx8 lo, hi;
#pragma unroll
      for (int j=0;j<4;++j){
        lo[j]   = (short)f2bf(vv0[j]);
        lo[j+4] = (short)f2bf(vv1[j]);
        hi[j]   = (short)f2bf(vv2[j]);
        hi[j+4] = (short)f2bf(vv3[j]);
      }
      size_t fb = ((size_t)(b*16 + h)*64 + (st*8 + wr*4 + m))*1024 + (size_t)lane*16;
      *(bfx8*)(Vf + fb) = lo;
      *(bfx8*)(Vf + fb + 8) = hi;
      __syncthreads();
    }
  }
}

// ---------------- Qr2 producer, write-coalesced: all 16 heads per block ----------------
__global__ __launch_bounds__(256) void k_qr(
    const unsigned short* __restrict__ Qf, const unsigned short* __restrict__ relk,
    unsigned short* __restrict__ Qr2)
{
  __shared__ __align__(16) unsigned short sst[16][16][24];
  const int bx = blockIdx.x;
  const int b  = bx & 3;
  const int st = (bx >> 2) & 63;
  const int uh = bx >> 8;
  const int w = threadIdx.x >> 6, lane = threadIdx.x & 63;
  const int p = lane & 15, g = lane >> 4;
  const int s0 = st << 4;
  const f4 fz = {0.f,0.f,0.f,0.f};

  bfx8 a0[4], a1[4];
#pragma unroll
  for (int hh=0; hh<4; ++hh){
    size_t fb = (((size_t)(b*16 + w*4 + hh))*64 + st)*1024 + (size_t)lane*16;
    a0[hh] = *(const bfx8*)(Qf + fb);
    a1[hh] = *(const bfx8*)(Qf + fb + 8);
  }

  const int c0 = uh ? 9 : 0;
  const int c1 = uh ? 17 : 9;
  const int so = threadIdx.x >> 4, uo = threadIdx.x & 15;

  for (int c=c0; c<c1; ++c){
    const int r0 = c << 4;
    bfx8 b0 = *(const bfx8*)(relk + (size_t)(r0 + p)*64 + 8*g);
    bfx8 b1 = *(const bfx8*)(relk + (size_t)(r0 + p)*64 + 32 + 8*g);
#pragma unroll
    for (int hh=0; hh<4; ++hh){
      f4 acc = mfma32(a1[hh], b1, mfma32(a0[hh], b0, fz));
#pragma unroll
      for (int r=0; r<4; ++r)
        sst[4*g + r][p][w*4 + hh] = f2bf(acc[r]);
    }
    __syncthreads();
    bfx8 v0 = *(const bfx8*)&sst[so][uo][0];
    bfx8 v1 = *(const bfx8*)&sst[so][uo][8];
    size_t ga = (((size_t)b*1024 + s0 + so)*272 + r0 + uo)*16;
    *(bfx8*)(Qr2 + ga) = v0;
    *(bfx8*)(Qr2 + ga + 8) = v1;
    __syncthreads();
  }
}

// ---------------- softmax denominator -> ivf; LDS-staged Q/K shared across 8 waves ----------------
__global__ __launch_bounds__(512, 4) void k_s(
    const unsigned short* __restrict__ Qf, const unsigned short* __restrict__ Kf,
    const unsigned short* __restrict__ Qr2, float* __restrict__ ivf)
{
  __shared__ __align__(16) unsigned short qs[2][2][1024];
  __shared__ __align__(16) unsigned short ks[2][4][1024];
  const int pbid = blockIdx.x;            // (stg<<6)|(ttg<<2)|b
  const int b   = pbid & 3;
  const int ttg = (pbid >> 2) & 15;
  const int stg = pbid >> 6;              // 0..31
  const int w = threadIdx.x >> 6, lane = threadIdx.x & 63;
  const int stl = w >> 2, ttl = w & 3;
  const int st = stg*2 + stl;
  const int tt = ttg*4 + ttl;
  const int p = lane & 15, g = lane >> 4;
  const int s = (st << 4) + p;
  const int t0 = tt << 4;
  const f4 fz = {0.f,0.f,0.f,0.f};

  bfx8 rv[4][2];
#pragma unroll
  for (int r=0; r<4; ++r){
    int t = t0 + 4*g + r;
    int u = s - t + 128; u = u < 0 ? 0 : (u > 256 ? 256 : u);
    const unsigned short* q = Qr2 + (((size_t)b*1024 + s)*272 + u)*16;
    rv[r][0] = *(const bfx8*)q;
    rv[r][1] = *(const bfx8*)(q + 8);
  }

  const bool stager = (w <= 1) || (w >= 4);
  const unsigned short* gsrc =
      (w <= 1) ? (Qf + ((size_t)(b*16)*64 + (stg*2 + w))*1024)
               : (Kf + ((size_t)(b*16)*64 + (ttg*4 + (w & 3)))*1024);
  unsigned short* ldst[2];
  ldst[0] = (w <= 1) ? &qs[0][w][0] : &ks[0][w & 3][0];
  ldst[1] = (w <= 1) ? &qs[1][w][0] : &ks[1][w & 3][0];

  if (stager){
    gload16(gsrc + (size_t)lane*8, ldst[0]);
    gload16(gsrc + 512 + (size_t)lane*8, ldst[0] + 512);
    asm volatile("s_waitcnt vmcnt(0)" ::: "memory");
  }
  __builtin_amdgcn_sched_barrier(0);
  __builtin_amdgcn_s_barrier();
  __builtin_amdgcn_sched_barrier(0);

  f4 ps = fz;
#pragma unroll
  for (int h=0; h<16; ++h){
    const int buf = h & 1;
    if (h < 15 && stager){
      unsigned short* ld = ldst[buf ^ 1];
      gload16(gsrc + (size_t)(h+1)*65536 + (size_t)lane*8, ld);
      gload16(gsrc + (size_t)(h+1)*65536 + 512 + (size_t)lane*8, ld + 512);
    }
    {
      const unsigned short* qb = &qs[buf][stl][lane*16];
      const unsigned short* kb = &ks[buf][ttl][lane*16];
      bfx8 q0 = *(const bfx8*)qb;
      bfx8 q1 = *(const bfx8*)(qb + 8);
      bfx8 k0 = *(const bfx8*)kb;
      bfx8 k1 = *(const bfx8*)(kb + 8);
      f4 sc = mfma32(k1, q1, mfma32(k0, q0, fz));
      const int hg = h >> 3, hr = h & 7;
#pragma unroll
      for (int r=0; r<4; ++r)
        ps[r] += __expf(sc[r] + bf2f((unsigned short)rv[r][hg][hr]));
    }
    if (h < 15){
      if (stager) asm volatile("s_waitcnt vmcnt(0)" ::: "memory");
      __builtin_amdgcn_sched_barrier(0);
      __builtin_amdgcn_s_barrier();
      __builtin_amdgcn_sched_barrier(0);
    }
  }

  f4 inv;
#pragma unroll
  for (int r=0; r<4; ++r) inv[r] = 1.0f / ps[r];
  *(f4*)(ivf + (((size_t)(b*64 + tt)*64 + st)*64 + lane)*4) = inv;
}

// ---------------- fused attention: ALL 64 t-tiles; 4 waves x 2 heads; unroll-2 set rotation ----------------
__global__ __launch_bounds__(256, 2) void k_attn(
    const unsigned short* __restrict__ Qf, const unsigned short* __restrict__ Kf,
    const unsigned short* __restrict__ Vf, const unsigned short* __restrict__ Qr2,
    const float* __restrict__ ivf, const unsigned short* __restrict__ relvT,
    const float* __restrict__ relv, unsigned short* __restrict__ out1)
{
  __shared__ __align__(16) unsigned short skew[128*264];   // 67,584 B
  const int pbid = blockIdx.x;
  const int xcd = pbid & 7;
  const int b = xcd >> 1;
  const int hhalf = (pbid >> 3) & 1;
  const int st = ((pbid >> 4) << 1) | (xcd & 1);
  const int s0 = st << 4;
  const int w = threadIdx.x >> 6;
  const int lane = threadIdx.x & 63;
  const int p = lane & 15, g = lane >> 4;
  const int s = s0 + p;
  const int hl0 = w * 2;                 // local head base (skew rows)
  const int h0 = hhalf*8 + hl0;          // global head base (memory)
  const f4 fz = {0.f,0.f,0.f,0.f};

  {
    unsigned* zp = (unsigned*)skew + w*4224;
    for (int i = lane; i < 4224; i += 64) zp[i] = 0u;
  }

  bfx8 qf[2][2]; float qr0[2], qr1[2];
#pragma unroll
  for (int hh=0; hh<2; ++hh){
    size_t qb = (((size_t)(b*16 + h0 + hh))*64 + st)*1024 + (size_t)lane*16;
    qf[hh][0] = *(const bfx8*)(Qf + qb);
    qf[hh][1] = *(const bfx8*)(Qf + qb + 8);
    qr0[hh] = bf2f(Qr2[(((size_t)b*1024 + s)*272 + 0)*16 + (h0+hh)]);
    qr1[hh] = bf2f(Qr2[(((size_t)b*1024 + s)*272 + 256)*16 + (h0+hh)]);
  }

  f4 o[2][4];
#pragma unroll
  for (int hh=0; hh<2; ++hh)
#pragma unroll
    for (int df=0; df<4; ++df) o[hh][df] = fz;

  float tl0[2] = {0.f,0.f};
  float tl1[2] = {0.f,0.f};

  const int tlo = (st-8 < 0) ? 0 : st-8;
  const int thi = (st+8 > 63) ? 63 : st+8;

  // double register sets, rotated by compile-time index (no v_mov rotation)
  bfx8 kc[2][2][2]; bfx8 vc8[2][2][2]; unsigned short qc[2][2][4]; f4 is[2];

  // prologue: prefetch tile 0 into set 0
#pragma unroll
  for (int hh=0; hh<2; ++hh){
    size_t bh = (size_t)(b*16 + h0 + hh);
    size_t fb = (bh*64 + 0)*1024 + (size_t)lane*16;
    kc[0][hh][0] = *(const bfx8*)(Kf + fb);
    kc[0][hh][1] = *(const bfx8*)(Kf + fb + 8);
    vc8[0][hh][0] = *(const bfx8*)(Vf + fb);
    vc8[0][hh][1] = *(const bfx8*)(Vf + fb + 8);
  }
  if (0 >= tlo){     // tile 0 in near band (st<=8)
#pragma unroll
    for (int hh=0; hh<2; ++hh)
#pragma unroll
      for (int r=0; r<4; ++r){
        int t = 4*g + r;
        int u = s - t + 128; u = u < 0 ? 0 : (u > 256 ? 256 : u);
        qc[0][hh][r] = Qr2[(((size_t)b*1024 + s)*272 + u)*16 + (h0+hh)];
      }
  }
  is[0] = *(const f4*)(ivf + (((size_t)(b*64 + 0)*64 + st)*64 + lane)*4);

  for (int tb = 0; tb < 32; ++tb){
#pragma unroll
    for (int sub = 0; sub < 2; ++sub){
      const int cur = sub, nxt = sub ^ 1;
      const int ti = tb*2 + sub;
      const int t0 = ti << 4;
      const bool nearT = (ti >= tlo) && (ti <= thi);

      if (ti < 63){
        const int tn = ti + 1;
#pragma unroll
        for (int hh=0; hh<2; ++hh){
          size_t bh = (size_t)(b*16 + h0 + hh);
          size_t fb = (bh*64 + tn)*1024 + (size_t)lane*16;
          kc[nxt][hh][0] = *(const bfx8*)(Kf + fb);
          kc[nxt][hh][1] = *(const bfx8*)(Kf + fb + 8);
          vc8[nxt][hh][0] = *(const bfx8*)(Vf + fb);
          vc8[nxt][hh][1] = *(const bfx8*)(Vf + fb + 8);
        }
        if (tn >= tlo && tn <= thi){
#pragma unroll
          for (int hh=0; hh<2; ++hh)
#pragma unroll
            for (int r=0; r<4; ++r){
              int t = (tn<<4) + 4*g + r;
              int u = s - t + 128; u = u < 0 ? 0 : (u > 256 ? 256 : u);
              qc[nxt][hh][r] = Qr2[(((size_t)b*1024 + s)*272 + u)*16 + (h0+hh)];
            }
        }
        is[nxt] = *(const f4*)(ivf + (((size_t)(b*64 + tn)*64 + st)*64 + lane)*4);
      }

      if (nearT){
#pragma unroll
        for (int hh=0; hh<2; ++hh){
          f4 sc = mfma32(kc[cur][hh][1], qf[hh][1], mfma32(kc[cur][hh][0], qf[hh][0], fz));
          f4 at;
#pragma unroll
          for (int r=0; r<4; ++r) at[r] = __expf(sc[r] + bf2f(qc[cur][hh][r])) * is[cur][r];
          const unsigned w0 = cvtpk(at[0], at[1]);
          const unsigned w1 = cvtpk(at[2], at[3]);
          const unsigned short abf[4] = {
            (unsigned short)(w0 & 0xffffu), (unsigned short)(w0 >> 16),
            (unsigned short)(w1 & 0xffffu), (unsigned short)(w1 >> 16) };
          const int row = (hl0 + hh)*16 + p;
#pragma unroll
          for (int r=0; r<4; ++r){
            int t = t0 + 4*g + r;
            int u = s - t + 128;
            if (u <= 0) tl0[hh] += at[r];
            else if (u >= 256) tl1[hh] += at[r];
            else skew[row*264 + u] = abf[r];
          }
          union { unsigned u[2]; bfx4 v; } cv;
          cv.u[0] = w0; cv.u[1] = w1;
          const bfx4 pk = cv.v;
          o[hh][0] = mfma16(lo4(vc8[cur][hh][0]), pk, o[hh][0]);
          o[hh][1] = mfma16(hi4(vc8[cur][hh][0]), pk, o[hh][1]);
          o[hh][2] = mfma16(lo4(vc8[cur][hh][1]), pk, o[hh][2]);
          o[hh][3] = mfma16(hi4(vc8[cur][hh][1]), pk, o[hh][3]);
        }
      } else {
        const bool hiSide = (ti < st);     // u >= 256 side
#pragma unroll
        for (int hh=0; hh<2; ++hh){
          f4 sc = mfma32(kc[cur][hh][1], qf[hh][1], mfma32(kc[cur][hh][0], qf[hh][0], fz));
          const float qa = hiSide ? qr1[hh] : qr0[hh];
          f4 at;
#pragma unroll
          for (int r=0; r<4; ++r) at[r] = __expf(sc[r] + qa) * is[cur][r];
          float tsum = at[0] + at[1] + at[2] + at[3];
          if (hiSide) tl1[hh] += tsum; else tl0[hh] += tsum;
          const unsigned w0 = cvtpk(at[0], at[1]);
          const unsigned w1 = cvtpk(at[2], at[3]);
          union { unsigned u[2]; bfx4 v; } cv;
          cv.u[0] = w0; cv.u[1] = w1;
          const bfx4 pk = cv.v;
          o[hh][0] = mfma16(lo4(vc8[cur][hh][0]), pk, o[hh][0]);
          o[hh][1] = mfma16(hi4(vc8[cur][hh][0]), pk, o[hh][1]);
          o[hh][2] = mfma16(lo4(vc8[cur][hh][1]), pk, o[hh][2]);
          o[hh][3] = mfma16(hi4(vc8[cur][hh][1]), pk, o[hh][3]);
        }
      }
    }
  }

  __syncthreads();

  // ---- fused out2 = rel_v^T @ skew (own-wave rows only; local head rows) ----
  f4 acc2[2][4];
#pragma unroll
  for (int hh=0; hh<2; ++hh)
#pragma unroll
    for (int df=0; df<4; ++df) acc2[hh][df] = fz;
#pragma unroll
  for (int k0=0; k0<256; k0+=32){
    bfx8 bb0 = *(const bfx8*)&skew[(hl0*16 + p)*264 + k0 + 8*g];
    bfx8 bb1 = *(const bfx8*)&skew[((hl0+1)*16 + p)*264 + k0 + 8*g];
#pragma unroll
    for (int df=0; df<4; ++df){
      bfx8 a = *(const bfx8*)(relvT + (size_t)(df*16 + p)*288 + k0 + 8*g);
      acc2[0][df] = mfma32(a, bb0, acc2[0][df]);
      acc2[1][df] = mfma32(a, bb1, acc2[1][df]);
    }
  }

  f4 rv0[4], rv1[4];
#pragma unroll
  for (int df=0; df<4; ++df){
    rv0[df] = *(const f4*)(relv + df*16 + 4*g);
    rv1[df] = *(const f4*)(relv + 16384 + df*16 + 4*g);
  }
#pragma unroll
  for (int hh=0; hh<2; ++hh){
    float tv0 = tl0[hh];
    tv0 += __shfl_xor(tv0, 16, 64);
    tv0 += __shfl_xor(tv0, 32, 64);
    float tv1 = tl1[hh];
    tv1 += __shfl_xor(tv1, 16, 64);
    tv1 += __shfl_xor(tv1, 32, 64);
#pragma unroll
    for (int df=0; df<4; ++df)
#pragma unroll
      for (int r=0; r<4; ++r)
        o[hh][df][r] += acc2[hh][df][r] + tv0*rv0[df][r] + tv1*rv1[df][r];
  }

  __syncthreads();

  float* slabBase = (float*)skew;
  float (*tb2)[68] = (float(*)[68])(slabBase + w*(16*68));
#pragma unroll
  for (int hh=0; hh<2; ++hh){
#pragma unroll
    for (int df=0; df<4; ++df)
      *(f4*)&tb2[p][df*16 + 4*g] = o[hh][df];
    __syncthreads();
    const int srow = lane >> 2, quad = lane & 3;
    f4 r0 = *(const f4*)&tb2[srow][quad*16 + 0];
    f4 r1 = *(const f4*)&tb2[srow][quad*16 + 4];
    f4 r2 = *(const f4*)&tb2[srow][quad*16 + 8];
    f4 r3 = *(const f4*)&tb2[srow][quad*16 + 12];
    size_t addr = ((size_t)b*1024 + s0 + srow)*1024 + (h0+hh)*64 + quad*16;
    bfx8 pa, pb;
#pragma unroll
    for (int j=0; j<4; ++j){
      pa[j]   = (short)f2bf(r0[j]);
      pa[j+4] = (short)f2bf(r1[j]);
      pb[j]   = (short)f2bf(r2[j]);
      pb[j+4] = (short)f2bf(r3[j]);
    }
    *(bfx8*)(out1 + addr) = pa;
    *(bfx8*)(out1 + addr + 8) = pb;
    __syncthreads();
  }
}

// ---------------- final projection: counted-vmcnt double-buffered pipeline ----------------
__global__ __launch_bounds__(256) void k_wo(
    const unsigned short* __restrict__ out1, const unsigned short* __restrict__ wo,
    const float* __restrict__ bo, float* __restrict__ dout)
{
  __shared__ __align__(16) unsigned short smem[2][6144];
  const int nt = blockIdx.x;
  const int mt = blockIdx.y;
  const int w = threadIdx.x >> 6, lane = threadIdx.x & 63;
  const int wr = w >> 1, wc = w & 1;
  const int p = lane & 15, g = lane >> 4;
  const int m0 = mt*64, n0 = nt*128;
  const f4 fz = {0.f,0.f,0.f,0.f};
  f4 acc[2][4];
#pragma unroll
  for (int m=0;m<2;++m)
#pragma unroll
    for (int n=0;n<4;++n) acc[m][n] = fz;

  const int j0 = w*2, j1 = w*2 + 1;
  const unsigned short* gA = out1 + (size_t)(m0 + p)*1024 + g*8;
  const unsigned short* gB = wo   + (size_t)(n0 + p)*1024 + g*8;

  {
    unsigned short* d0 = &smem[0][0];
    gload16(gA + (size_t)w*16384, d0 + w*512);
    gload16(gB + (size_t)j0*16384, d0 + 2048 + j0*512);
    gload16(gB + (size_t)j1*16384, d0 + 2048 + j1*512);
  }

  for (int it=0; it<32; ++it){
    const int cur = it & 1;
    if (it < 31){
      const int kn = (it+1)*32;
      unsigned short* dn = &smem[cur^1][0];
      gload16(gA + (size_t)w*16384 + kn, dn + w*512);
      gload16(gB + (size_t)j0*16384 + kn, dn + 2048 + j0*512);
      gload16(gB + (size_t)j1*16384 + kn, dn + 2048 + j1*512);
      asm volatile("s_waitcnt vmcnt(3)" ::: "memory");
    } else {
      asm volatile("s_waitcnt vmcnt(0)" ::: "memory");
    }
    __builtin_amdgcn_sched_barrier(0);
    __builtin_amdgcn_s_barrier();
    __builtin_amdgcn_sched_barrier(0);
    {
      const unsigned short* Ab = &smem[cur][0];
      bfx8 af[2], bfr[4];
#pragma unroll
      for (int m=0;m<2;++m) af[m] = *(const bfx8*)(Ab + (wr*2+m)*512 + lane*8);
#pragma unroll
      for (int n=0;n<4;++n) bfr[n] = *(const bfx8*)(Ab + 2048 + (wc*4+n)*512 + lane*8);
#pragma unroll
      for (int m=0;m<2;++m)
#pragma unroll
        for (int n=0;n<4;++n)
          acc[m][n] = mfma32(af[m], bfr[n], acc[m][n]);
    }
    __builtin_amdgcn_sched_barrier(0);
    __builtin_amdgcn_s_barrier();
    __builtin_amdgcn_sched_barrier(0);
  }

#pragma unroll
  for (int n=0;n<4;++n){
    const int col = n0 + wc*64 + n*16 + p;
    const float bias = bo[col];
#pragma unroll
    for (int m=0;m<2;++m)
#pragma unroll
      for (int r=0;r<4;++r){
        int row = m0 + wr*32 + m*16 + 4*g + r;
        int bb = row >> 10, s = row & 1023;
        dout[((size_t)s*4 + bb)*1024 + col] = acc[m][n][r] + bias;
      }
  }
}

extern "C" void kernel_launch(void* const* d_in, const int* in_sizes, int n_in,
                              void* d_out, int out_size, void* d_ws, size_t ws_size,
                              hipStream_t stream){
  const float* x   = (const float*)d_in[0];
  const float* wq  = (const float*)d_in[1];
  const float* wk  = (const float*)d_in[2];
  const float* wv  = (const float*)d_in[3];
  const float* wo  = (const float*)d_in[4];
  const float* bo  = (const float*)d_in[5];
  const float* rlk = (const float*)d_in[6];
  const float* rlv = (const float*)d_in[7];
  char* ws = (char*)d_ws;

  unsigned short* x_bf    = (unsigned short*)(ws + 0);
  unsigned short* wq_bf   = (unsigned short*)(ws + 8388608);   // [wq|wk|wv|wo] contiguous
  unsigned short* relk_bf = (unsigned short*)(ws + 16777216);
  unsigned short* relvT_bf= (unsigned short*)(ws + 16812032);
  unsigned short* Qf      = (unsigned short*)(ws + 16848896);   // fragment layout
  unsigned short* Kf      = (unsigned short*)(ws + 25237504);   // fragment layout
  unsigned short* Vf      = (unsigned short*)(ws + 33626112);   // fragment layout
  unsigned short* Qr2     = (unsigned short*)(ws + 42014720);   // 35.65 MB -> 77666304
  unsigned short* out1    = (unsigned short*)(ws + 113317888);  // 8 MB
  float*          ivf     = (float*)        (ws + 121706496);  // 16 MB -> 138483712
  unsigned short* wo_bf   = (unsigned short*)(ws + 14680064);

  k_prep<<<8264, 256, 0, stream>>>(x, wq, wk, wv, wo, rlk, rlv,
                                   x_bf, wq_bf, relk_bf, relvT_bf);

  k_qkv<<<dim3(24,4,8), 256, 0, stream>>>(x_bf, wq_bf, Qf, Kf, Vf);
  k_qr<<<512, 256, 0, stream>>>(Qf, relk_bf, Qr2);

  k_s   <<<2048, 512, 0, stream>>>(Qf, Kf, Qr2, ivf);
  k_attn<<<512, 256, 0, stream>>>(Qf, Kf, Vf, Qr2, ivf, relvT_bf, rlv, out1);
  k_wo<<<dim3(8,64), 256, 0, stream>>>(out1, wo_bf, bo, (float*)d_out);
}

// Round 19
// 217.646 us; speedup vs baseline: 1.0041x; 1.0041x over previous
//
#include <hip/hip_runtime.h>
#include <stdint.h>

#define DI __device__ __forceinline__

typedef __attribute__((ext_vector_type(8))) short bfx8;
typedef __attribute__((ext_vector_type(4))) short bfx4;
typedef __attribute__((ext_vector_type(4))) float f4;

DI unsigned short f2bf(float x){
  unsigned u = __float_as_uint(x);
  u = (u + 0x7FFFu + ((u >> 16) & 1u)) >> 16;
  return (unsigned short)u;
}
DI float bf2f(unsigned short h){ return __uint_as_float(((unsigned)h) << 16); }

// packed RNE f32->bf16x2 (same rounding as f2bf)
DI unsigned cvtpk(float lo, float hi){
  unsigned r;
  asm("v_cvt_pk_bf16_f32 %0, %1, %2" : "=v"(r) : "v"(lo), "v"(hi));
  return r;
}

DI f4 mfma32(bfx8 a, bfx8 b, f4 c){
  return __builtin_amdgcn_mfma_f32_16x16x32_bf16(a, b, c, 0, 0, 0);
}
#if __has_builtin(__builtin_amdgcn_mfma_f32_16x16x16bf16_1k)
DI f4 mfma16(bfx4 a, bfx4 b, f4 c){
  return __builtin_amdgcn_mfma_f32_16x16x16bf16_1k(a, b, c, 0, 0, 0);
}
#else
DI f4 mfma16(bfx4 a, bfx4 b, f4 c){
  f4 d = c;
  asm volatile("v_mfma_f32_16x16x16_bf16 %0, %1, %2, %0" : "+v"(d) : "v"(a), "v"(b));
  return d;
}
#endif

DI bfx4 lo4(bfx8 v){ bfx4 r; r[0]=v[0]; r[1]=v[1]; r[2]=v[2]; r[3]=v[3]; return r; }
DI bfx4 hi4(bfx8 v){ bfx4 r; r[0]=v[4]; r[1]=v[5]; r[2]=v[6]; r[3]=v[7]; return r; }

// async global->LDS, 16B per lane; LDS dest = wave-uniform base + lane*16
DI void gload16(const void* g, void* l){
  __builtin_amdgcn_global_load_lds(
      (__attribute__((address_space(1))) void*)g,
      (__attribute__((address_space(3))) void*)l, 16, 0, 0);
}

// Fragment layouts (all 16-bit elems):
//   Qf/Kf[bh][tile][lane][16]: elem[kf*8+j] = M[tile*16 + (lane&15)][kf*32 + 8*(lane>>4) + j]
//   Vf  [bh][tile][lane][16]: elem[df*4+j] = V[tile*16 + 4*(lane>>4) + j][df*16 + (lane&15)]
//   ivf [b][tt][st][lane][4]: elem[r] = 1/S at (s = st*16 + (lane&15), t = tt*16 + 4*(lane>>4) + r)

// ---------------- merged prep: x cast | 4 weight casts | rel tables ----------------
__global__ void k_prep(const float* __restrict__ x,
                       const float* __restrict__ wq, const float* __restrict__ wk,
                       const float* __restrict__ wv, const float* __restrict__ wo,
                       const float* __restrict__ rlk, const float* __restrict__ rlv,
                       unsigned short* __restrict__ x_bf, unsigned short* __restrict__ w_bf,
                       unsigned short* __restrict__ relk_bf, unsigned short* __restrict__ relvT_bf){
  const int bid = blockIdx.x;
  if (bid < 4096){
    int i = bid*256 + threadIdx.x;
    const float4 v = ((const float4*)x)[i];
    bfx4 o;
    o[0] = (short)f2bf(v.x); o[1] = (short)f2bf(v.y);
    o[2] = (short)f2bf(v.z); o[3] = (short)f2bf(v.w);
    *(bfx4*)(x_bf + (size_t)i*4) = o;
  } else if (bid < 8192){
    const int wb = (bid - 4096) >> 10;
    const float* src = (wb==0) ? wq : (wb==1) ? wk : (wb==2) ? wv : wo;
    int i = ((bid - 4096) & 1023)*256 + threadIdx.x;
    const float4 v = ((const float4*)src)[i];
    bfx4 o;
    o[0] = (short)f2bf(v.x); o[1] = (short)f2bf(v.y);
    o[2] = (short)f2bf(v.z); o[3] = (short)f2bf(v.w);
    *(bfx4*)(w_bf + (size_t)wb*1048576 + (size_t)i*4) = o;
  } else {
    int i = (bid - 8192)*256 + threadIdx.x;
    if (i < 272*64){
      int r = i >> 6, d = i & 63;
      relk_bf[i] = (r < 257) ? f2bf(rlk[r*64 + d]) : (unsigned short)0;
    }
    if (i < 64*288){
      int d = i / 288, r = i % 288;
      relvT_bf[i] = (r < 257) ? f2bf(rlv[(size_t)r*64 + d]) : (unsigned short)0;
    }
  }
}

// ---------------- QKV projections: depth-2 triple-buffered counted-vmcnt pipeline ----------------
__global__ __launch_bounds__(256, 3) void k_qkv(
    const unsigned short* __restrict__ xbf, const unsigned short* __restrict__ wqkv,
    unsigned short* __restrict__ Qf, unsigned short* __restrict__ Kf,
    unsigned short* __restrict__ Vf)
{
  __shared__ __align__(16) unsigned short smem[3][8192];   // 3 x 16 KB: A blocks 0-7, B blocks 8-15
  const int nt = blockIdx.x;
  const int b  = blockIdx.y;
  const int st = blockIdx.z;
  const int w = threadIdx.x >> 6, lane = threadIdx.x & 63;
  const int wr = w >> 1, wc = w & 1;
  const int p = lane & 15, g = lane >> 4;
  const int s0 = st*128;
  const int n0 = nt*128;
  const f4 fz = {0.f,0.f,0.f,0.f};
  f4 acc[4][4];
#pragma unroll
  for (int m=0;m<4;++m)
#pragma unroll
    for (int n=0;n<4;++n) acc[m][n] = fz;

  const int j0 = w*2, j1 = w*2 + 1;
  const unsigned short* gA = xbf  + (size_t)((s0 + p)*4 + b)*1024 + g*8;
  const unsigned short* gB = wqkv + (size_t)(n0 + p)*1024 + g*8;

  // prologue: stage tiles 0 and 1
#pragma unroll
  for (int t0=0; t0<2; ++t0){
    unsigned short* d0 = &smem[t0][0];
    const int kk = t0*32;
    gload16(gA + (size_t)j0*65536 + kk, d0 + j0*512);
    gload16(gA + (size_t)j1*65536 + kk, d0 + j1*512);
    gload16(gB + (size_t)j0*16384 + kk, d0 + 4096 + j0*512);
    gload16(gB + (size_t)j1*16384 + kk, d0 + 4096 + j1*512);
  }

  int cur = 0, nxt2 = 2;
  for (int it=0; it<32; ++it){
    if (it < 30){
      const int kn = (it+2)*32;
      unsigned short* dn = &smem[nxt2][0];
      gload16(gA + (size_t)j0*65536 + kn, dn + j0*512);
      gload16(gA + (size_t)j1*65536 + kn, dn + j1*512);
      gload16(gB + (size_t)j0*16384 + kn, dn + 4096 + j0*512);
      gload16(gB + (size_t)j1*16384 + kn, dn + 4096 + j1*512);
      asm volatile("s_waitcnt vmcnt(8)" ::: "memory");   // cur done; 2 tiles in flight
    } else if (it == 30){
      asm volatile("s_waitcnt vmcnt(4)" ::: "memory");
    } else {
      asm volatile("s_waitcnt vmcnt(0)" ::: "memory");
    }
    __builtin_amdgcn_sched_barrier(0);
    __builtin_amdgcn_s_barrier();
    __builtin_amdgcn_sched_barrier(0);
    {
      const unsigned short* Ab = &smem[cur][0];
      bfx8 af[4], bfr[4];
#pragma unroll
      for (int m=0;m<4;++m) af[m] = *(const bfx8*)(Ab + (wr*4+m)*512 + lane*8);
#pragma unroll
      for (int n=0;n<4;++n) bfr[n] = *(const bfx8*)(Ab + 4096 + (wc*4+n)*512 + lane*8);
#pragma unroll
      for (int m=0;m<4;++m)
#pragma unroll
        for (int n=0;n<4;++n)
          acc[m][n] = mfma32(af[m], bfr[n], acc[m][n]);
    }
    __builtin_amdgcn_sched_barrier(0);
    __builtin_amdgcn_s_barrier();
    __builtin_amdgcn_sched_barrier(0);
    cur = (cur == 2) ? 0 : cur + 1;
    nxt2 = (nxt2 == 2) ? 0 : nxt2 + 1;
  }

  const int n64 = n0 + wc*64;
  const int sec = n64 >> 10;            // 0 Q, 1 K, 2 V
  const int h = (n64 & 1023) >> 6;
  float* es = (float*)&smem[0][0] + w*1280;

  if (sec < 2){
    const float scl = (sec == 0) ? 0.125f : 1.0f;
    unsigned short* dst = (sec == 0) ? Qf : Kf;
#pragma unroll
    for (int m=0;m<4;++m){
#pragma unroll
      for (int n=0;n<4;++n)
#pragma unroll
        for (int r=0;r<4;++r)
          es[(4*g + r)*80 + 16*n + p] = acc[m][n][r] * scl;
      __syncthreads();
      f4 v0 = *(const f4*)&es[p*80 + 8*g];
      f4 v1 = *(const f4*)&es[p*80 + 8*g + 4];
      f4 v2 = *(const f4*)&es[p*80 + 32 + 8*g];
      f4 v3 = *(const f4*)&es[p*80 + 32 + 8*g + 4];
      bfx8 lo, hi;
#pragma unroll
      for (int j=0;j<4;++j){
        lo[j]   = (short)f2bf(v0[j]);
        lo[j+4] = (short)f2bf(v1[j]);
        hi[j]   = (short)f2bf(v2[j]);
        hi[j+4] = (short)f2bf(v3[j]);
      }
      size_t fb = ((size_t)(b*16 + h)*64 + (st*8 + wr*4 + m))*1024 + (size_t)lane*16;
      *(bfx8*)(dst + fb) = lo;
      *(bfx8*)(dst + fb + 8) = hi;
      __syncthreads();
    }
  } else {
#pragma unroll
    for (int m=0;m<4;++m){
#pragma unroll
      for (int n=0;n<4;++n)
        *(f4*)&es[(16*n + p)*20 + 4*g] = acc[m][n];
      __syncthreads();
      f4 vv0 = *(const f4*)&es[(p)*20 + 4*g];
      f4 vv1 = *(const f4*)&es[(16 + p)*20 + 4*g];
      f4 vv2 = *(const f4*)&es[(32 + p)*20 + 4*g];
      f4 vv3 = *(const f4*)&es[(48 + p)*20 + 4*g];
      bfx8 lo, hi;
#pragma unroll
      for (int j=0;j<4;++j){
        lo[j]   = (short)f2bf(vv0[j]);
        lo[j+4] = (short)f2bf(vv1[j]);
        hi[j]   = (short)f2bf(vv2[j]);
        hi[j+4] = (short)f2bf(vv3[j]);
      }
      size_t fb = ((size_t)(b*16 + h)*64 + (st*8 + wr*4 + m))*1024 + (size_t)lane*16;
      *(bfx8*)(Vf + fb) = lo;
      *(bfx8*)(Vf + fb + 8) = hi;
      __syncthreads();
    }
  }
}

// ---------------- Qr2 producer, write-coalesced: all 16 heads per block ----------------
__global__ __launch_bounds__(256) void k_qr(
    const unsigned short* __restrict__ Qf, const unsigned short* __restrict__ relk,
    unsigned short* __restrict__ Qr2)
{
  __shared__ __align__(16) unsigned short sst[16][16][24];
  const int bx = blockIdx.x;
  const int b  = bx & 3;
  const int st = (bx >> 2) & 63;
  const int uh = bx >> 8;
  const int w = threadIdx.x >> 6, lane = threadIdx.x & 63;
  const int p = lane & 15, g = lane >> 4;
  const int s0 = st << 4;
  const f4 fz = {0.f,0.f,0.f,0.f};

  bfx8 a0[4], a1[4];
#pragma unroll
  for (int hh=0; hh<4; ++hh){
    size_t fb = (((size_t)(b*16 + w*4 + hh))*64 + st)*1024 + (size_t)lane*16;
    a0[hh] = *(const bfx8*)(Qf + fb);
    a1[hh] = *(const bfx8*)(Qf + fb + 8);
  }

  const int c0 = uh ? 9 : 0;
  const int c1 = uh ? 17 : 9;
  const int so = threadIdx.x >> 4, uo = threadIdx.x & 15;

  for (int c=c0; c<c1; ++c){
    const int r0 = c << 4;
    bfx8 b0 = *(const bfx8*)(relk + (size_t)(r0 + p)*64 + 8*g);
    bfx8 b1 = *(const bfx8*)(relk + (size_t)(r0 + p)*64 + 32 + 8*g);
#pragma unroll
    for (int hh=0; hh<4; ++hh){
      f4 acc = mfma32(a1[hh], b1, mfma32(a0[hh], b0, fz));
#pragma unroll
      for (int r=0; r<4; ++r)
        sst[4*g + r][p][w*4 + hh] = f2bf(acc[r]);
    }
    __syncthreads();
    bfx8 v0 = *(const bfx8*)&sst[so][uo][0];
    bfx8 v1 = *(const bfx8*)&sst[so][uo][8];
    size_t ga = (((size_t)b*1024 + s0 + so)*272 + r0 + uo)*16;
    *(bfx8*)(Qr2 + ga) = v0;
    *(bfx8*)(Qr2 + ga + 8) = v1;
    __syncthreads();
  }
}

// ---------------- softmax denominator -> ivf; LDS-staged Q/K shared across 8 waves ----------------
__global__ __launch_bounds__(512, 4) void k_s(
    const unsigned short* __restrict__ Qf, const unsigned short* __restrict__ Kf,
    const unsigned short* __restrict__ Qr2, float* __restrict__ ivf)
{
  __shared__ __align__(16) unsigned short qs[2][2][1024];
  __shared__ __align__(16) unsigned short ks[2][4][1024];
  const int pbid = blockIdx.x;            // (stg<<6)|(ttg<<2)|b
  const int b   = pbid & 3;
  const int ttg = (pbid >> 2) & 15;
  const int stg = pbid >> 6;              // 0..31
  const int w = threadIdx.x >> 6, lane = threadIdx.x & 63;
  const int stl = w >> 2, ttl = w & 3;
  const int st = stg*2 + stl;
  const int tt = ttg*4 + ttl;
  const int p = lane & 15, g = lane >> 4;
  const int s = (st << 4) + p;
  const int t0 = tt << 4;
  const f4 fz = {0.f,0.f,0.f,0.f};

  bfx8 rv[4][2];
#pragma unroll
  for (int r=0; r<4; ++r){
    int t = t0 + 4*g + r;
    int u = s - t + 128; u = u < 0 ? 0 : (u > 256 ? 256 : u);
    const unsigned short* q = Qr2 + (((size_t)b*1024 + s)*272 + u)*16;
    rv[r][0] = *(const bfx8*)q;
    rv[r][1] = *(const bfx8*)(q + 8);
  }

  const bool stager = (w <= 1) || (w >= 4);
  const unsigned short* gsrc =
      (w <= 1) ? (Qf + ((size_t)(b*16)*64 + (stg*2 + w))*1024)
               : (Kf + ((size_t)(b*16)*64 + (ttg*4 + (w & 3)))*1024);
  unsigned short* ldst[2];
  ldst[0] = (w <= 1) ? &qs[0][w][0] : &ks[0][w & 3][0];
  ldst[1] = (w <= 1) ? &qs[1][w][0] : &ks[1][w & 3][0];

  if (stager){
    gload16(gsrc + (size_t)lane*8, ldst[0]);
    gload16(gsrc + 512 + (size_t)lane*8, ldst[0] + 512);
    asm volatile("s_waitcnt vmcnt(0)" ::: "memory");
  }
  __builtin_amdgcn_sched_barrier(0);
  __builtin_amdgcn_s_barrier();
  __builtin_amdgcn_sched_barrier(0);

  f4 ps = fz;
#pragma unroll
  for (int h=0; h<16; ++h){
    const int buf = h & 1;
    if (h < 15 && stager){
      unsigned short* ld = ldst[buf ^ 1];
      gload16(gsrc + (size_t)(h+1)*65536 + (size_t)lane*8, ld);
      gload16(gsrc + (size_t)(h+1)*65536 + 512 + (size_t)lane*8, ld + 512);
    }
    {
      const unsigned short* qb = &qs[buf][stl][lane*16];
      const unsigned short* kb = &ks[buf][ttl][lane*16];
      bfx8 q0 = *(const bfx8*)qb;
      bfx8 q1 = *(const bfx8*)(qb + 8);
      bfx8 k0 = *(const bfx8*)kb;
      bfx8 k1 = *(const bfx8*)(kb + 8);
      f4 sc = mfma32(k1, q1, mfma32(k0, q0, fz));
      const int hg = h >> 3, hr = h & 7;
#pragma unroll
      for (int r=0; r<4; ++r)
        ps[r] += __expf(sc[r] + bf2f((unsigned short)rv[r][hg][hr]));
    }
    if (h < 15){
      if (stager) asm volatile("s_waitcnt vmcnt(0)" ::: "memory");
      __builtin_amdgcn_sched_barrier(0);
      __builtin_amdgcn_s_barrier();
      __builtin_amdgcn_sched_barrier(0);
    }
  }

  f4 inv;
#pragma unroll
  for (int r=0; r<4; ++r) inv[r] = 1.0f / ps[r];
  *(f4*)(ivf + (((size_t)(b*64 + tt)*64 + st)*64 + lane)*4) = inv;
}

// ---------------- fused attention: ALL 64 t-tiles; 4 waves x 2 heads; unroll-2 set rotation ----------------
__global__ __launch_bounds__(256, 2) void k_attn(
    const unsigned short* __restrict__ Qf, const unsigned short* __restrict__ Kf,
    const unsigned short* __restrict__ Vf, const unsigned short* __restrict__ Qr2,
    const float* __restrict__ ivf, const unsigned short* __restrict__ relvT,
    const float* __restrict__ relv, unsigned short* __restrict__ out1)
{
  __shared__ __align__(16) unsigned short skew[128*264];   // 67,584 B
  const int pbid = blockIdx.x;
  const int xcd = pbid & 7;
  const int b = xcd >> 1;
  const int hhalf = (pbid >> 3) & 1;
  const int st = ((pbid >> 4) << 1) | (xcd & 1);
  const int s0 = st << 4;
  const int w = threadIdx.x >> 6;
  const int lane = threadIdx.x & 63;
  const int p = lane & 15, g = lane >> 4;
  const int s = s0 + p;
  const int hl0 = w * 2;                 // local head base (skew rows)
  const int h0 = hhalf*8 + hl0;          // global head base (memory)
  const f4 fz = {0.f,0.f,0.f,0.f};

  {
    unsigned* zp = (unsigned*)skew + w*4224;
    for (int i = lane; i < 4224; i += 64) zp[i] = 0u;
  }

  bfx8 qf[2][2]; float qr0[2], qr1[2];
#pragma unroll
  for (int hh=0; hh<2; ++hh){
    size_t qb = (((size_t)(b*16 + h0 + hh))*64 + st)*1024 + (size_t)lane*16;
    qf[hh][0] = *(const bfx8*)(Qf + qb);
    qf[hh][1] = *(const bfx8*)(Qf + qb + 8);
    qr0[hh] = bf2f(Qr2[(((size_t)b*1024 + s)*272 + 0)*16 + (h0+hh)]);
    qr1[hh] = bf2f(Qr2[(((size_t)b*1024 + s)*272 + 256)*16 + (h0+hh)]);
  }

  f4 o[2][4];
#pragma unroll
  for (int hh=0; hh<2; ++hh)
#pragma unroll
    for (int df=0; df<4; ++df) o[hh][df] = fz;

  float tl0[2] = {0.f,0.f};
  float tl1[2] = {0.f,0.f};

  const int tlo = (st-8 < 0) ? 0 : st-8;
  const int thi = (st+8 > 63) ? 63 : st+8;

  // double register sets, rotated by compile-time index (no v_mov rotation)
  bfx8 kc[2][2][2]; bfx8 vc8[2][2][2]; unsigned short qc[2][2][4]; f4 is[2];

  // prologue: prefetch tile 0 into set 0
#pragma unroll
  for (int hh=0; hh<2; ++hh){
    size_t bh = (size_t)(b*16 + h0 + hh);
    size_t fb = (bh*64 + 0)*1024 + (size_t)lane*16;
    kc[0][hh][0] = *(const bfx8*)(Kf + fb);
    kc[0][hh][1] = *(const bfx8*)(Kf + fb + 8);
    vc8[0][hh][0] = *(const bfx8*)(Vf + fb);
    vc8[0][hh][1] = *(const bfx8*)(Vf + fb + 8);
  }
  if (0 >= tlo){     // tile 0 in near band (st<=8)
#pragma unroll
    for (int hh=0; hh<2; ++hh)
#pragma unroll
      for (int r=0; r<4; ++r){
        int t = 4*g + r;
        int u = s - t + 128; u = u < 0 ? 0 : (u > 256 ? 256 : u);
        qc[0][hh][r] = Qr2[(((size_t)b*1024 + s)*272 + u)*16 + (h0+hh)];
      }
  }
  is[0] = *(const f4*)(ivf + (((size_t)(b*64 + 0)*64 + st)*64 + lane)*4);

  for (int tb = 0; tb < 32; ++tb){
#pragma unroll
    for (int sub = 0; sub < 2; ++sub){
      const int cur = sub, nxt = sub ^ 1;
      const int ti = tb*2 + sub;
      const int t0 = ti << 4;
      const bool nearT = (ti >= tlo) && (ti <= thi);

      if (ti < 63){
        const int tn = ti + 1;
#pragma unroll
        for (int hh=0; hh<2; ++hh){
          size_t bh = (size_t)(b*16 + h0 + hh);
          size_t fb = (bh*64 + tn)*1024 + (size_t)lane*16;
          kc[nxt][hh][0] = *(const bfx8*)(Kf + fb);
          kc[nxt][hh][1] = *(const bfx8*)(Kf + fb + 8);
          vc8[nxt][hh][0] = *(const bfx8*)(Vf + fb);
          vc8[nxt][hh][1] = *(const bfx8*)(Vf + fb + 8);
        }
        if (tn >= tlo && tn <= thi){
#pragma unroll
          for (int hh=0; hh<2; ++hh)
#pragma unroll
            for (int r=0; r<4; ++r){
              int t = (tn<<4) + 4*g + r;
              int u = s - t + 128; u = u < 0 ? 0 : (u > 256 ? 256 : u);
              qc[nxt][hh][r] = Qr2[(((size_t)b*1024 + s)*272 + u)*16 + (h0+hh)];
            }
        }
        is[nxt] = *(const f4*)(ivf + (((size_t)(b*64 + tn)*64 + st)*64 + lane)*4);
      }

      if (nearT){
#pragma unroll
        for (int hh=0; hh<2; ++hh){
          f4 sc = mfma32(kc[cur][hh][1], qf[hh][1], mfma32(kc[cur][hh][0], qf[hh][0], fz));
          f4 at;
#pragma unroll
          for (int r=0; r<4; ++r) at[r] = __expf(sc[r] + bf2f(qc[cur][hh][r])) * is[cur][r];
          const unsigned w0 = cvtpk(at[0], at[1]);
          const unsigned w1 = cvtpk(at[2], at[3]);
          const unsigned short abf[4] = {
            (unsigned short)(w0 & 0xffffu), (unsigned short)(w0 >> 16),
            (unsigned short)(w1 & 0xffffu), (unsigned short)(w1 >> 16) };
          const int row = (hl0 + hh)*16 + p;
#pragma unroll
          for (int r=0; r<4; ++r){
            int t = t0 + 4*g + r;
            int u = s - t + 128;
            if (u <= 0) tl0[hh] += at[r];
            else if (u >= 256) tl1[hh] += at[r];
            else skew[row*264 + u] = abf[r];
          }
          union { unsigned u[2]; bfx4 v; } cv;
          cv.u[0] = w0; cv.u[1] = w1;
          const bfx4 pk = cv.v;
          o[hh][0] = mfma16(lo4(vc8[cur][hh][0]), pk, o[hh][0]);
          o[hh][1] = mfma16(hi4(vc8[cur][hh][0]), pk, o[hh][1]);
          o[hh][2] = mfma16(lo4(vc8[cur][hh][1]), pk, o[hh][2]);
          o[hh][3] = mfma16(hi4(vc8[cur][hh][1]), pk, o[hh][3]);
        }
      } else {
        const bool hiSide = (ti < st);     // u >= 256 side
#pragma unroll
        for (int hh=0; hh<2; ++hh){
          f4 sc = mfma32(kc[cur][hh][1], qf[hh][1], mfma32(kc[cur][hh][0], qf[hh][0], fz));
          const float qa = hiSide ? qr1[hh] : qr0[hh];
          f4 at;
#pragma unroll
          for (int r=0; r<4; ++r) at[r] = __expf(sc[r] + qa) * is[cur][r];
          float tsum = at[0] + at[1] + at[2] + at[3];
          if (hiSide) tl1[hh] += tsum; else tl0[hh] += tsum;
          const unsigned w0 = cvtpk(at[0], at[1]);
          const unsigned w1 = cvtpk(at[2], at[3]);
          union { unsigned u[2]; bfx4 v; } cv;
          cv.u[0] = w0; cv.u[1] = w1;
          const bfx4 pk = cv.v;
          o[hh][0] = mfma16(lo4(vc8[cur][hh][0]), pk, o[hh][0]);
          o[hh][1] = mfma16(hi4(vc8[cur][hh][0]), pk, o[hh][1]);
          o[hh][2] = mfma16(lo4(vc8[cur][hh][1]), pk, o[hh][2]);
          o[hh][3] = mfma16(hi4(vc8[cur][hh][1]), pk, o[hh][3]);
        }
      }
    }
  }

  __syncthreads();

  // ---- fused out2 = rel_v^T @ skew (own-wave rows only; local head rows) ----
  f4 acc2[2][4];
#pragma unroll
  for (int hh=0; hh<2; ++hh)
#pragma unroll
    for (int df=0; df<4; ++df) acc2[hh][df] = fz;
#pragma unroll
  for (int k0=0; k0<256; k0+=32){
    bfx8 bb0 = *(const bfx8*)&skew[(hl0*16 + p)*264 + k0 + 8*g];
    bfx8 bb1 = *(const bfx8*)&skew[((hl0+1)*16 + p)*264 + k0 + 8*g];
#pragma unroll
    for (int df=0; df<4; ++df){
      bfx8 a = *(const bfx8*)(relvT + (size_t)(df*16 + p)*288 + k0 + 8*g);
      acc2[0][df] = mfma32(a, bb0, acc2[0][df]);
      acc2[1][df] = mfma32(a, bb1, acc2[1][df]);
    }
  }

  f4 rv0[4], rv1[4];
#pragma unroll
  for (int df=0; df<4; ++df){
    rv0[df] = *(const f4*)(relv + df*16 + 4*g);
    rv1[df] = *(const f4*)(relv + 16384 + df*16 + 4*g);
  }
#pragma unroll
  for (int hh=0; hh<2; ++hh){
    float tv0 = tl0[hh];
    tv0 += __shfl_xor(tv0, 16, 64);
    tv0 += __shfl_xor(tv0, 32, 64);
    float tv1 = tl1[hh];
    tv1 += __shfl_xor(tv1, 16, 64);
    tv1 += __shfl_xor(tv1, 32, 64);
#pragma unroll
    for (int df=0; df<4; ++df)
#pragma unroll
      for (int r=0; r<4; ++r)
        o[hh][df][r] += acc2[hh][df][r] + tv0*rv0[df][r] + tv1*rv1[df][r];
  }

  __syncthreads();

  float* slabBase = (float*)skew;
  float (*tb2)[68] = (float(*)[68])(slabBase + w*(16*68));
#pragma unroll
  for (int hh=0; hh<2; ++hh){
#pragma unroll
    for (int df=0; df<4; ++df)
      *(f4*)&tb2[p][df*16 + 4*g] = o[hh][df];
    __syncthreads();
    const int srow = lane >> 2, quad = lane & 3;
    f4 r0 = *(const f4*)&tb2[srow][quad*16 + 0];
    f4 r1 = *(const f4*)&tb2[srow][quad*16 + 4];
    f4 r2 = *(const f4*)&tb2[srow][quad*16 + 8];
    f4 r3 = *(const f4*)&tb2[srow][quad*16 + 12];
    size_t addr = ((size_t)b*1024 + s0 + srow)*1024 + (h0+hh)*64 + quad*16;
    bfx8 pa, pb;
#pragma unroll
    for (int j=0; j<4; ++j){
      pa[j]   = (short)f2bf(r0[j]);
      pa[j+4] = (short)f2bf(r1[j]);
      pb[j]   = (short)f2bf(r2[j]);
      pb[j+4] = (short)f2bf(r3[j]);
    }
    *(bfx8*)(out1 + addr) = pa;
    *(bfx8*)(out1 + addr + 8) = pb;
    __syncthreads();
  }
}

// ---------------- final projection: depth-2 triple-buffered counted-vmcnt pipeline ----------------
__global__ __launch_bounds__(256) void k_wo(
    const unsigned short* __restrict__ out1, const unsigned short* __restrict__ wo,
    const float* __restrict__ bo, float* __restrict__ dout)
{
  __shared__ __align__(16) unsigned short smem[3][6144];   // 3 x 12 KB: A blocks 0-3, B blocks 4-11
  const int nt = blockIdx.x;
  const int mt = blockIdx.y;
  const int w = threadIdx.x >> 6, lane = threadIdx.x & 63;
  const int wr = w >> 1, wc = w & 1;
  const int p = lane & 15, g = lane >> 4;
  const int m0 = mt*64, n0 = nt*128;
  const f4 fz = {0.f,0.f,0.f,0.f};
  f4 acc[2][4];
#pragma unroll
  for (int m=0;m<2;++m)
#pragma unroll
    for (int n=0;n<4;++n) acc[m][n] = fz;

  const int j0 = w*2, j1 = w*2 + 1;
  const unsigned short* gA = out1 + (size_t)(m0 + p)*1024 + g*8;
  const unsigned short* gB = wo   + (size_t)(n0 + p)*1024 + g*8;

#pragma unroll
  for (int t0=0; t0<2; ++t0){
    unsigned short* d0 = &smem[t0][0];
    const int kk = t0*32;
    gload16(gA + (size_t)w*16384 + kk, d0 + w*512);
    gload16(gB + (size_t)j0*16384 + kk, d0 + 2048 + j0*512);
    gload16(gB + (size_t)j1*16384 + kk, d0 + 2048 + j1*512);
  }

  int cur = 0, nxt2 = 2;
  for (int it=0; it<32; ++it){
    if (it < 30){
      const int kn = (it+2)*32;
      unsigned short* dn = &smem[nxt2][0];
      gload16(gA + (size_t)w*16384 + kn, dn + w*512);
      gload16(gB + (size_t)j0*16384 + kn, dn + 2048 + j0*512);
      gload16(gB + (size_t)j1*16384 + kn, dn + 2048 + j1*512);
      asm volatile("s_waitcnt vmcnt(6)" ::: "memory");
    } else if (it == 30){
      asm volatile("s_waitcnt vmcnt(3)" ::: "memory");
    } else {
      asm volatile("s_waitcnt vmcnt(0)" ::: "memory");
    }
    __builtin_amdgcn_sched_barrier(0);
    __builtin_amdgcn_s_barrier();
    __builtin_amdgcn_sched_barrier(0);
    {
      const unsigned short* Ab = &smem[cur][0];
      bfx8 af[2], bfr[4];
#pragma unroll
      for (int m=0;m<2;++m) af[m] = *(const bfx8*)(Ab + (wr*2+m)*512 + lane*8);
#pragma unroll
      for (int n=0;n<4;++n) bfr[n] = *(const bfx8*)(Ab + 2048 + (wc*4+n)*512 + lane*8);
#pragma unroll
      for (int m=0;m<2;++m)
#pragma unroll
        for (int n=0;n<4;++n)
          acc[m][n] = mfma32(af[m], bfr[n], acc[m][n]);
    }
    __builtin_amdgcn_sched_barrier(0);
    __builtin_amdgcn_s_barrier();
    __builtin_amdgcn_sched_barrier(0);
    cur = (cur == 2) ? 0 : cur + 1;
    nxt2 = (nxt2 == 2) ? 0 : nxt2 + 1;
  }

#pragma unroll
  for (int n=0;n<4;++n){
    const int col = n0 + wc*64 + n*16 + p;
    const float bias = bo[col];
#pragma unroll
    for (int m=0;m<2;++m)
#pragma unroll
      for (int r=0;r<4;++r){
        int row = m0 + wr*32 + m*16 + 4*g + r;
        int bb = row >> 10, s = row & 1023;
        dout[((size_t)s*4 + bb)*1024 + col] = acc[m][n][r] + bias;
      }
  }
}

extern "C" void kernel_launch(void* const* d_in, const int* in_sizes, int n_in,
                              void* d_out, int out_size, void* d_ws, size_t ws_size,
                              hipStream_t stream){
  const float* x   = (const float*)d_in[0];
  const float* wq  = (const float*)d_in[1];
  const float* wk  = (const float*)d_in[2];
  const float* wv  = (const float*)d_in[3];
  const float* wo  = (const float*)d_in[4];
  const float* bo  = (const float*)d_in[5];
  const float* rlk = (const float*)d_in[6];
  const float* rlv = (const float*)d_in[7];
  char* ws = (char*)d_ws;

  unsigned short* x_bf    = (unsigned short*)(ws + 0);
  unsigned short* wq_bf   = (unsigned short*)(ws + 8388608);   // [wq|wk|wv|wo] contiguous
  unsigned short* relk_bf = (unsigned short*)(ws + 16777216);
  unsigned short* relvT_bf= (unsigned short*)(ws + 16812032);
  unsigned short* Qf      = (unsigned short*)(ws + 16848896);   // fragment layout
  unsigned short* Kf      = (unsigned short*)(ws + 25237504);   // fragment layout
  unsigned short* Vf      = (unsigned short*)(ws + 33626112);   // fragment layout
  unsigned short* Qr2     = (unsigned short*)(ws + 42014720);   // 35.65 MB -> 77666304
  unsigned short* out1    = (unsigned short*)(ws + 113317888);  // 8 MB
  float*          ivf     = (float*)        (ws + 121706496);  // 16 MB -> 138483712
  unsigned short* wo_bf   = (unsigned short*)(ws + 14680064);

  k_prep<<<8264, 256, 0, stream>>>(x, wq, wk, wv, wo, rlk, rlv,
                                   x_bf, wq_bf, relk_bf, relvT_bf);

  k_qkv<<<dim3(24,4,8), 256, 0, stream>>>(x_bf, wq_bf, Qf, Kf, Vf);
  k_qr<<<512, 256, 0, stream>>>(Qf, relk_bf, Qr2);

  k_s   <<<2048, 512, 0, stream>>>(Qf, Kf, Qr2, ivf);
  k_attn<<<512, 256, 0, stream>>>(Qf, Kf, Vf, Qr2, ivf, relvT_bf, rlv, out1);
  k_wo<<<dim3(8,64), 256, 0, stream>>>(out1, wo_bf, bo, (float*)d_out);
}

// Round 21
// 217.472 us; speedup vs baseline: 1.0049x; 1.0008x over previous
//
#include <hip/hip_runtime.h>
#include <stdint.h>

#define DI __device__ __forceinline__

typedef __attribute__((ext_vector_type(8))) short bfx8;
typedef __attribute__((ext_vector_type(4))) short bfx4;
typedef __attribute__((ext_vector_type(4))) float f4;

DI unsigned short f2bf(float x){
  unsigned u = __float_as_uint(x);
  u = (u + 0x7FFFu + ((u >> 16) & 1u)) >> 16;
  return (unsigned short)u;
}
DI float bf2f(unsigned short h){ return __uint_as_float(((unsigned)h) << 16); }

// packed RNE f32->bf16x2 (same rounding as f2bf)
DI unsigned cvtpk(float lo, float hi){
  unsigned r;
  asm("v_cvt_pk_bf16_f32 %0, %1, %2" : "=v"(r) : "v"(lo), "v"(hi));
  return r;
}

DI f4 mfma32(bfx8 a, bfx8 b, f4 c){
  return __builtin_amdgcn_mfma_f32_16x16x32_bf16(a, b, c, 0, 0, 0);
}
#if __has_builtin(__builtin_amdgcn_mfma_f32_16x16x16bf16_1k)
DI f4 mfma16(bfx4 a, bfx4 b, f4 c){
  return __builtin_amdgcn_mfma_f32_16x16x16bf16_1k(a, b, c, 0, 0, 0);
}
#else
DI f4 mfma16(bfx4 a, bfx4 b, f4 c){
  f4 d = c;
  asm volatile("v_mfma_f32_16x16x16_bf16 %0, %1, %2, %0" : "+v"(d) : "v"(a), "v"(b));
  return d;
}
#endif

DI bfx4 lo4(bfx8 v){ bfx4 r; r[0]=v[0]; r[1]=v[1]; r[2]=v[2]; r[3]=v[3]; return r; }
DI bfx4 hi4(bfx8 v){ bfx4 r; r[0]=v[4]; r[1]=v[5]; r[2]=v[6]; r[3]=v[7]; return r; }

// async global->LDS, 16B per lane; LDS dest = wave-uniform base + lane*16
DI void gload16(const void* g, void* l){
  __builtin_amdgcn_global_load_lds(
      (__attribute__((address_space(1))) void*)g,
      (__attribute__((address_space(3))) void*)l, 16, 0, 0);
}

// Fragment layouts (all 16-bit elems):
//   Qf/Kf[bh][tile][lane][16]: elem[kf*8+j] = M[tile*16 + (lane&15)][kf*32 + 8*(lane>>4) + j]
//   Vf  [bh][tile][lane][16]: elem[df*4+j] = V[tile*16 + 4*(lane>>4) + j][df*16 + (lane&15)]
//   ivf [b][tt][st][lane][4]: elem[r] = 1/S at (s = st*16 + (lane&15), t = tt*16 + 4*(lane>>4) + r)

// ---------------- merged prep: x cast | 4 weight casts | rel tables ----------------
__global__ void k_prep(const float* __restrict__ x,
                       const float* __restrict__ wq, const float* __restrict__ wk,
                       const float* __restrict__ wv, const float* __restrict__ wo,
                       const float* __restrict__ rlk, const float* __restrict__ rlv,
                       unsigned short* __restrict__ x_bf, unsigned short* __restrict__ w_bf,
                       unsigned short* __restrict__ relk_bf, unsigned short* __restrict__ relvT_bf){
  const int bid = blockIdx.x;
  if (bid < 4096){
    int i = bid*256 + threadIdx.x;
    const float4 v = ((const float4*)x)[i];
    bfx4 o;
    o[0] = (short)f2bf(v.x); o[1] = (short)f2bf(v.y);
    o[2] = (short)f2bf(v.z); o[3] = (short)f2bf(v.w);
    *(bfx4*)(x_bf + (size_t)i*4) = o;
  } else if (bid < 8192){
    const int wb = (bid - 4096) >> 10;
    const float* src = (wb==0) ? wq : (wb==1) ? wk : (wb==2) ? wv : wo;
    int i = ((bid - 4096) & 1023)*256 + threadIdx.x;
    const float4 v = ((const float4*)src)[i];
    bfx4 o;
    o[0] = (short)f2bf(v.x); o[1] = (short)f2bf(v.y);
    o[2] = (short)f2bf(v.z); o[3] = (short)f2bf(v.w);
    *(bfx4*)(w_bf + (size_t)wb*1048576 + (size_t)i*4) = o;
  } else {
    int i = (bid - 8192)*256 + threadIdx.x;
    if (i < 272*64){
      int r = i >> 6, d = i & 63;
      relk_bf[i] = (r < 257) ? f2bf(rlk[r*64 + d]) : (unsigned short)0;
    }
    if (i < 64*288){
      int d = i / 288, r = i % 288;
      relvT_bf[i] = (r < 257) ? f2bf(rlv[(size_t)r*64 + d]) : (unsigned short)0;
    }
  }
}

// ---------------- QKV projections: depth-2 triple-buffered counted-vmcnt pipeline ----------------
__global__ __launch_bounds__(256, 3) void k_qkv(
    const unsigned short* __restrict__ xbf, const unsigned short* __restrict__ wqkv,
    unsigned short* __restrict__ Qf, unsigned short* __restrict__ Kf,
    unsigned short* __restrict__ Vf)
{
  __shared__ __align__(16) unsigned short smem[3][8192];   // 3 x 16 KB: A blocks 0-7, B blocks 8-15
  const int nt = blockIdx.x;
  const int b  = blockIdx.y;
  const int st = blockIdx.z;
  const int w = threadIdx.x >> 6, lane = threadIdx.x & 63;
  const int wr = w >> 1, wc = w & 1;
  const int p = lane & 15, g = lane >> 4;
  const int s0 = st*128;
  const int n0 = nt*128;
  const f4 fz = {0.f,0.f,0.f,0.f};
  f4 acc[4][4];
#pragma unroll
  for (int m=0;m<4;++m)
#pragma unroll
    for (int n=0;n<4;++n) acc[m][n] = fz;

  const int j0 = w*2, j1 = w*2 + 1;
  const unsigned short* gA = xbf  + (size_t)((s0 + p)*4 + b)*1024 + g*8;
  const unsigned short* gB = wqkv + (size_t)(n0 + p)*1024 + g*8;

  // prologue: stage tiles 0 and 1
#pragma unroll
  for (int t0=0; t0<2; ++t0){
    unsigned short* d0 = &smem[t0][0];
    const int kk = t0*32;
    gload16(gA + (size_t)j0*65536 + kk, d0 + j0*512);
    gload16(gA + (size_t)j1*65536 + kk, d0 + j1*512);
    gload16(gB + (size_t)j0*16384 + kk, d0 + 4096 + j0*512);
    gload16(gB + (size_t)j1*16384 + kk, d0 + 4096 + j1*512);
  }

  int cur = 0, nxt2 = 2;
  for (int it=0; it<32; ++it){
    if (it < 30){
      const int kn = (it+2)*32;
      unsigned short* dn = &smem[nxt2][0];
      gload16(gA + (size_t)j0*65536 + kn, dn + j0*512);
      gload16(gA + (size_t)j1*65536 + kn, dn + j1*512);
      gload16(gB + (size_t)j0*16384 + kn, dn + 4096 + j0*512);
      gload16(gB + (size_t)j1*16384 + kn, dn + 4096 + j1*512);
      asm volatile("s_waitcnt vmcnt(8)" ::: "memory");   // cur done; 2 tiles in flight
    } else if (it == 30){
      asm volatile("s_waitcnt vmcnt(4)" ::: "memory");
    } else {
      asm volatile("s_waitcnt vmcnt(0)" ::: "memory");
    }
    __builtin_amdgcn_sched_barrier(0);
    __builtin_amdgcn_s_barrier();
    __builtin_amdgcn_sched_barrier(0);
    {
      const unsigned short* Ab = &smem[cur][0];
      bfx8 af[4], bfr[4];
#pragma unroll
      for (int m=0;m<4;++m) af[m] = *(const bfx8*)(Ab + (wr*4+m)*512 + lane*8);
#pragma unroll
      for (int n=0;n<4;++n) bfr[n] = *(const bfx8*)(Ab + 4096 + (wc*4+n)*512 + lane*8);
#pragma unroll
      for (int m=0;m<4;++m)
#pragma unroll
        for (int n=0;n<4;++n)
          acc[m][n] = mfma32(af[m], bfr[n], acc[m][n]);
    }
    __builtin_amdgcn_sched_barrier(0);
    __builtin_amdgcn_s_barrier();
    __builtin_amdgcn_sched_barrier(0);
    cur = (cur == 2) ? 0 : cur + 1;
    nxt2 = (nxt2 == 2) ? 0 : nxt2 + 1;
  }

  const int n64 = n0 + wc*64;
  const int sec = n64 >> 10;            // 0 Q, 1 K, 2 V
  const int h = (n64 & 1023) >> 6;
  float* es = (float*)&smem[0][0] + w*1280;

  if (sec < 2){
    const float scl = (sec == 0) ? 0.125f : 1.0f;
    unsigned short* dst = (sec == 0) ? Qf : Kf;
#pragma unroll
    for (int m=0;m<4;++m){
#pragma unroll
      for (int n=0;n<4;++n)
#pragma unroll
        for (int r=0;r<4;++r)
          es[(4*g + r)*80 + 16*n + p] = acc[m][n][r] * scl;
      __syncthreads();
      f4 v0 = *(const f4*)&es[p*80 + 8*g];
      f4 v1 = *(const f4*)&es[p*80 + 8*g + 4];
      f4 v2 = *(const f4*)&es[p*80 + 32 + 8*g];
      f4 v3 = *(const f4*)&es[p*80 + 32 + 8*g + 4];
      bfx8 lo, hi;
#pragma unroll
      for (int j=0;j<4;++j){
        lo[j]   = (short)f2bf(v0[j]);
        lo[j+4] = (short)f2bf(v1[j]);
        hi[j]   = (short)f2bf(v2[j]);
        hi[j+4] = (short)f2bf(v3[j]);
      }
      size_t fb = ((size_t)(b*16 + h)*64 + (st*8 + wr*4 + m))*1024 + (size_t)lane*16;
      *(bfx8*)(dst + fb) = lo;
      *(bfx8*)(dst + fb + 8) = hi;
      __syncthreads();
    }
  } else {
#pragma unroll
    for (int m=0;m<4;++m){
#pragma unroll
      for (int n=0;n<4;++n)
        *(f4*)&es[(16*n + p)*20 + 4*g] = acc[m][n];
      __syncthreads();
      f4 vv0 = *(const f4*)&es[(p)*20 + 4*g];
      f4 vv1 = *(const f4*)&es[(16 + p)*20 + 4*g];
      f4 vv2 = *(const f4*)&es[(32 + p)*20 + 4*g];
      f4 vv3 = *(const f4*)&es[(48 + p)*20 + 4*g];
      bfx8 lo, hi;
#pragma unroll
      for (int j=0;j<4;++j){
        lo[j]   = (short)f2bf(vv0[j]);
        lo[j+4] = (short)f2bf(vv1[j]);
        hi[j]   = (short)f2bf(vv2[j]);
        hi[j+4] = (short)f2bf(vv3[j]);
      }
      size_t fb = ((size_t)(b*16 + h)*64 + (st*8 + wr*4 + m))*1024 + (size_t)lane*16;
      *(bfx8*)(Vf + fb) = lo;
      *(bfx8*)(Vf + fb + 8) = hi;
      __syncthreads();
    }
  }
}

// ---------------- Qr2 producer, write-coalesced: all 16 heads per block ----------------
__global__ __launch_bounds__(256) void k_qr(
    const unsigned short* __restrict__ Qf, const unsigned short* __restrict__ relk,
    unsigned short* __restrict__ Qr2)
{
  __shared__ __align__(16) unsigned short sst[16][16][24];
  const int bx = blockIdx.x;
  const int b  = bx & 3;
  const int st = (bx >> 2) & 63;
  const int uh = bx >> 8;
  const int w = threadIdx.x >> 6, lane = threadIdx.x & 63;
  const int p = lane & 15, g = lane >> 4;
  const int s0 = st << 4;
  const f4 fz = {0.f,0.f,0.f,0.f};

  bfx8 a0[4], a1[4];
#pragma unroll
  for (int hh=0; hh<4; ++hh){
    size_t fb = (((size_t)(b*16 + w*4 + hh))*64 + st)*1024 + (size_t)lane*16;
    a0[hh] = *(const bfx8*)(Qf + fb);
    a1[hh] = *(const bfx8*)(Qf + fb + 8);
  }

  const int c0 = uh ? 9 : 0;
  const int c1 = uh ? 17 : 9;
  const int so = threadIdx.x >> 4, uo = threadIdx.x & 15;

  for (int c=c0; c<c1; ++c){
    const int r0 = c << 4;
    bfx8 b0 = *(const bfx8*)(relk + (size_t)(r0 + p)*64 + 8*g);
    bfx8 b1 = *(const bfx8*)(relk + (size_t)(r0 + p)*64 + 32 + 8*g);
#pragma unroll
    for (int hh=0; hh<4; ++hh){
      f4 acc = mfma32(a1[hh], b1, mfma32(a0[hh], b0, fz));
#pragma unroll
      for (int r=0; r<4; ++r)
        sst[4*g + r][p][w*4 + hh] = f2bf(acc[r]);
    }
    __syncthreads();
    bfx8 v0 = *(const bfx8*)&sst[so][uo][0];
    bfx8 v1 = *(const bfx8*)&sst[so][uo][8];
    size_t ga = (((size_t)b*1024 + s0 + so)*272 + r0 + uo)*16;
    *(bfx8*)(Qr2 + ga) = v0;
    *(bfx8*)(Qr2 + ga + 8) = v1;
    __syncthreads();
  }
}

// ---------------- softmax denominator -> ivf; LDS-staged Q/K shared across 8 waves ----------------
__global__ __launch_bounds__(512, 4) void k_s(
    const unsigned short* __restrict__ Qf, const unsigned short* __restrict__ Kf,
    const unsigned short* __restrict__ Qr2, float* __restrict__ ivf)
{
  __shared__ __align__(16) unsigned short qs[2][2][1024];
  __shared__ __align__(16) unsigned short ks[2][4][1024];
  const int pbid = blockIdx.x;            // (stg<<6)|(ttg<<2)|b
  const int b   = pbid & 3;
  const int ttg = (pbid >> 2) & 15;
  const int stg = pbid >> 6;              // 0..31
  const int w = threadIdx.x >> 6, lane = threadIdx.x & 63;
  const int stl = w >> 2, ttl = w & 3;
  const int st = stg*2 + stl;
  const int tt = ttg*4 + ttl;
  const int p = lane & 15, g = lane >> 4;
  const int s = (st << 4) + p;
  const int t0 = tt << 4;
  const f4 fz = {0.f,0.f,0.f,0.f};

  bfx8 rv[4][2];
#pragma unroll
  for (int r=0; r<4; ++r){
    int t = t0 + 4*g + r;
    int u = s - t + 128; u = u < 0 ? 0 : (u > 256 ? 256 : u);
    const unsigned short* q = Qr2 + (((size_t)b*1024 + s)*272 + u)*16;
    rv[r][0] = *(const bfx8*)q;
    rv[r][1] = *(const bfx8*)(q + 8);
  }

  const bool stager = (w <= 1) || (w >= 4);
  const unsigned short* gsrc =
      (w <= 1) ? (Qf + ((size_t)(b*16)*64 + (stg*2 + w))*1024)
               : (Kf + ((size_t)(b*16)*64 + (ttg*4 + (w & 3)))*1024);
  unsigned short* ldst[2];
  ldst[0] = (w <= 1) ? &qs[0][w][0] : &ks[0][w & 3][0];
  ldst[1] = (w <= 1) ? &qs[1][w][0] : &ks[1][w & 3][0];

  if (stager){
    gload16(gsrc + (size_t)lane*8, ldst[0]);
    gload16(gsrc + 512 + (size_t)lane*8, ldst[0] + 512);
    asm volatile("s_waitcnt vmcnt(0)" ::: "memory");
  }
  __builtin_amdgcn_sched_barrier(0);
  __builtin_amdgcn_s_barrier();
  __builtin_amdgcn_sched_barrier(0);

  f4 ps = fz;
#pragma unroll
  for (int h=0; h<16; ++h){
    const int buf = h & 1;
    if (h < 15 && stager){
      unsigned short* ld = ldst[buf ^ 1];
      gload16(gsrc + (size_t)(h+1)*65536 + (size_t)lane*8, ld);
      gload16(gsrc + (size_t)(h+1)*65536 + 512 + (size_t)lane*8, ld + 512);
    }
    {
      const unsigned short* qb = &qs[buf][stl][lane*16];
      const unsigned short* kb = &ks[buf][ttl][lane*16];
      bfx8 q0 = *(const bfx8*)qb;
      bfx8 q1 = *(const bfx8*)(qb + 8);
      bfx8 k0 = *(const bfx8*)kb;
      bfx8 k1 = *(const bfx8*)(kb + 8);
      f4 sc = mfma32(k1, q1, mfma32(k0, q0, fz));
      const int hg = h >> 3, hr = h & 7;
#pragma unroll
      for (int r=0; r<4; ++r)
        ps[r] += __expf(sc[r] + bf2f((unsigned short)rv[r][hg][hr]));
    }
    if (h < 15){
      if (stager) asm volatile("s_waitcnt vmcnt(0)" ::: "memory");
      __builtin_amdgcn_sched_barrier(0);
      __builtin_amdgcn_s_barrier();
      __builtin_amdgcn_sched_barrier(0);
    }
  }

  f4 inv;
#pragma unroll
  for (int r=0; r<4; ++r) inv[r] = 1.0f / ps[r];
  *(f4*)(ivf + (((size_t)(b*64 + tt)*64 + st)*64 + lane)*4) = inv;
}

// ---------------- fused attention: ALL 64 t-tiles; 4 waves x 2 heads; unroll-2 set rotation ----------------
__global__ __launch_bounds__(256, 2) void k_attn(
    const unsigned short* __restrict__ Qf, const unsigned short* __restrict__ Kf,
    const unsigned short* __restrict__ Vf, const unsigned short* __restrict__ Qr2,
    const float* __restrict__ ivf, const unsigned short* __restrict__ relvT,
    const float* __restrict__ relv, unsigned short* __restrict__ out1)
{
  __shared__ __align__(16) unsigned short skew[128*264];   // 67,584 B
  const int pbid = blockIdx.x;
  const int xcd = pbid & 7;
  const int b = xcd >> 1;
  const int hhalf = (pbid >> 3) & 1;
  const int st = ((pbid >> 4) << 1) | (xcd & 1);
  const int s0 = st << 4;
  const int w = threadIdx.x >> 6;
  const int lane = threadIdx.x & 63;
  const int p = lane & 15, g = lane >> 4;
  const int s = s0 + p;
  const int hl0 = w * 2;                 // local head base (skew rows)
  const int h0 = hhalf*8 + hl0;          // global head base (memory)
  const f4 fz = {0.f,0.f,0.f,0.f};

  {
    unsigned* zp = (unsigned*)skew + w*4224;
    for (int i = lane; i < 4224; i += 64) zp[i] = 0u;
  }

  bfx8 qf[2][2]; float qr0[2], qr1[2];
#pragma unroll
  for (int hh=0; hh<2; ++hh){
    size_t qb = (((size_t)(b*16 + h0 + hh))*64 + st)*1024 + (size_t)lane*16;
    qf[hh][0] = *(const bfx8*)(Qf + qb);
    qf[hh][1] = *(const bfx8*)(Qf + qb + 8);
    qr0[hh] = bf2f(Qr2[(((size_t)b*1024 + s)*272 + 0)*16 + (h0+hh)]);
    qr1[hh] = bf2f(Qr2[(((size_t)b*1024 + s)*272 + 256)*16 + (h0+hh)]);
  }

  f4 o[2][4];
#pragma unroll
  for (int hh=0; hh<2; ++hh)
#pragma unroll
    for (int df=0; df<4; ++df) o[hh][df] = fz;

  float tl0[2] = {0.f,0.f};
  float tl1[2] = {0.f,0.f};

  const int tlo = (st-8 < 0) ? 0 : st-8;
  const int thi = (st+8 > 63) ? 63 : st+8;

  // double register sets, rotated by compile-time index (no v_mov rotation)
  bfx8 kc[2][2][2]; bfx8 vc8[2][2][2]; unsigned short qc[2][2][4]; f4 is[2];

  // prologue: prefetch tile 0 into set 0
#pragma unroll
  for (int hh=0; hh<2; ++hh){
    size_t bh = (size_t)(b*16 + h0 + hh);
    size_t fb = (bh*64 + 0)*1024 + (size_t)lane*16;
    kc[0][hh][0] = *(const bfx8*)(Kf + fb);
    kc[0][hh][1] = *(const bfx8*)(Kf + fb + 8);
    vc8[0][hh][0] = *(const bfx8*)(Vf + fb);
    vc8[0][hh][1] = *(const bfx8*)(Vf + fb + 8);
  }
  if (0 >= tlo){     // tile 0 in near band (st<=8)
#pragma unroll
    for (int hh=0; hh<2; ++hh)
#pragma unroll
      for (int r=0; r<4; ++r){
        int t = 4*g + r;
        int u = s - t + 128; u = u < 0 ? 0 : (u > 256 ? 256 : u);
        qc[0][hh][r] = Qr2[(((size_t)b*1024 + s)*272 + u)*16 + (h0+hh)];
      }
  }
  is[0] = *(const f4*)(ivf + (((size_t)(b*64 + 0)*64 + st)*64 + lane)*4);

  for (int tb = 0; tb < 32; ++tb){
#pragma unroll
    for (int sub = 0; sub < 2; ++sub){
      const int cur = sub, nxt = sub ^ 1;
      const int ti = tb*2 + sub;
      const int t0 = ti << 4;
      const bool nearT = (ti >= tlo) && (ti <= thi);

      if (ti < 63){
        const int tn = ti + 1;
#pragma unroll
        for (int hh=0; hh<2; ++hh){
          size_t bh = (size_t)(b*16 + h0 + hh);
          size_t fb = (bh*64 + tn)*1024 + (size_t)lane*16;
          kc[nxt][hh][0] = *(const bfx8*)(Kf + fb);
          kc[nxt][hh][1] = *(const bfx8*)(Kf + fb + 8);
          vc8[nxt][hh][0] = *(const bfx8*)(Vf + fb);
          vc8[nxt][hh][1] = *(const bfx8*)(Vf + fb + 8);
        }
        if (tn >= tlo && tn <= thi){
#pragma unroll
          for (int hh=0; hh<2; ++hh)
#pragma unroll
            for (int r=0; r<4; ++r){
              int t = (tn<<4) + 4*g + r;
              int u = s - t + 128; u = u < 0 ? 0 : (u > 256 ? 256 : u);
              qc[nxt][hh][r] = Qr2[(((size_t)b*1024 + s)*272 + u)*16 + (h0+hh)];
            }
        }
        is[nxt] = *(const f4*)(ivf + (((size_t)(b*64 + tn)*64 + st)*64 + lane)*4);
      }

      if (nearT){
#pragma unroll
        for (int hh=0; hh<2; ++hh){
          f4 sc = mfma32(kc[cur][hh][1], qf[hh][1], mfma32(kc[cur][hh][0], qf[hh][0], fz));
          f4 at;
#pragma unroll
          for (int r=0; r<4; ++r) at[r] = __expf(sc[r] + bf2f(qc[cur][hh][r])) * is[cur][r];
          const unsigned w0 = cvtpk(at[0], at[1]);
          const unsigned w1 = cvtpk(at[2], at[3]);
          const unsigned short abf[4] = {
            (unsigned short)(w0 & 0xffffu), (unsigned short)(w0 >> 16),
            (unsigned short)(w1 & 0xffffu), (unsigned short)(w1 >> 16) };
          const int row = (hl0 + hh)*16 + p;
#pragma unroll
          for (int r=0; r<4; ++r){
            int t = t0 + 4*g + r;
            int u = s - t + 128;
            if (u <= 0) tl0[hh] += at[r];
            else if (u >= 256) tl1[hh] += at[r];
            else skew[row*264 + u] = abf[r];
          }
          union { unsigned u[2]; bfx4 v; } cv;
          cv.u[0] = w0; cv.u[1] = w1;
          const bfx4 pk = cv.v;
          o[hh][0] = mfma16(lo4(vc8[cur][hh][0]), pk, o[hh][0]);
          o[hh][1] = mfma16(hi4(vc8[cur][hh][0]), pk, o[hh][1]);
          o[hh][2] = mfma16(lo4(vc8[cur][hh][1]), pk, o[hh][2]);
          o[hh][3] = mfma16(hi4(vc8[cur][hh][1]), pk, o[hh][3]);
        }
      } else {
        const bool hiSide = (ti < st);     // u >= 256 side
#pragma unroll
        for (int hh=0; hh<2; ++hh){
          f4 sc = mfma32(kc[cur][hh][1], qf[hh][1], mfma32(kc[cur][hh][0], qf[hh][0], fz));
          const float qa = hiSide ? qr1[hh] : qr0[hh];
          f4 at;
#pragma unroll
          for (int r=0; r<4; ++r) at[r] = __expf(sc[r] + qa) * is[cur][r];
          float tsum = at[0] + at[1] + at[2] + at[3];
          if (hiSide) tl1[hh] += tsum; else tl0[hh] += tsum;
          const unsigned w0 = cvtpk(at[0], at[1]);
          const unsigned w1 = cvtpk(at[2], at[3]);
          union { unsigned u[2]; bfx4 v; } cv;
          cv.u[0] = w0; cv.u[1] = w1;
          const bfx4 pk = cv.v;
          o[hh][0] = mfma16(lo4(vc8[cur][hh][0]), pk, o[hh][0]);
          o[hh][1] = mfma16(hi4(vc8[cur][hh][0]), pk, o[hh][1]);
          o[hh][2] = mfma16(lo4(vc8[cur][hh][1]), pk, o[hh][2]);
          o[hh][3] = mfma16(hi4(vc8[cur][hh][1]), pk, o[hh][3]);
        }
      }
    }
  }

  __syncthreads();

  // ---- fused out2 = rel_v^T @ skew (own-wave rows only; local head rows) ----
  f4 acc2[2][4];
#pragma unroll
  for (int hh=0; hh<2; ++hh)
#pragma unroll
    for (int df=0; df<4; ++df) acc2[hh][df] = fz;
#pragma unroll
  for (int k0=0; k0<256; k0+=32){
    bfx8 bb0 = *(const bfx8*)&skew[(hl0*16 + p)*264 + k0 + 8*g];
    bfx8 bb1 = *(const bfx8*)&skew[((hl0+1)*16 + p)*264 + k0 + 8*g];
#pragma unroll
    for (int df=0; df<4; ++df){
      bfx8 a = *(const bfx8*)(relvT + (size_t)(df*16 + p)*288 + k0 + 8*g);
      acc2[0][df] = mfma32(a, bb0, acc2[0][df]);
      acc2[1][df] = mfma32(a, bb1, acc2[1][df]);
    }
  }

  f4 rv0[4], rv1[4];
#pragma unroll
  for (int df=0; df<4; ++df){
    rv0[df] = *(const f4*)(relv + df*16 + 4*g);
    rv1[df] = *(const f4*)(relv + 16384 + df*16 + 4*g);
  }
#pragma unroll
  for (int hh=0; hh<2; ++hh){
    float tv0 = tl0[hh];
    tv0 += __shfl_xor(tv0, 16, 64);
    tv0 += __shfl_xor(tv0, 32, 64);
    float tv1 = tl1[hh];
    tv1 += __shfl_xor(tv1, 16, 64);
    tv1 += __shfl_xor(tv1, 32, 64);
#pragma unroll
    for (int df=0; df<4; ++df)
#pragma unroll
      for (int r=0; r<4; ++r)
        o[hh][df][r] += acc2[hh][df][r] + tv0*rv0[df][r] + tv1*rv1[df][r];
  }

  __syncthreads();

  float* slabBase = (float*)skew;
  float (*tb2)[68] = (float(*)[68])(slabBase + w*(16*68));
#pragma unroll
  for (int hh=0; hh<2; ++hh){
#pragma unroll
    for (int df=0; df<4; ++df)
      *(f4*)&tb2[p][df*16 + 4*g] = o[hh][df];
    __syncthreads();
    const int srow = lane >> 2, quad = lane & 3;
    f4 r0 = *(const f4*)&tb2[srow][quad*16 + 0];
    f4 r1 = *(const f4*)&tb2[srow][quad*16 + 4];
    f4 r2 = *(const f4*)&tb2[srow][quad*16 + 8];
    f4 r3 = *(const f4*)&tb2[srow][quad*16 + 12];
    size_t addr = ((size_t)b*1024 + s0 + srow)*1024 + (h0+hh)*64 + quad*16;
    bfx8 pa, pb;
#pragma unroll
    for (int j=0; j<4; ++j){
      pa[j]   = (short)f2bf(r0[j]);
      pa[j+4] = (short)f2bf(r1[j]);
      pb[j]   = (short)f2bf(r2[j]);
      pb[j+4] = (short)f2bf(r3[j]);
    }
    *(bfx8*)(out1 + addr) = pa;
    *(bfx8*)(out1 + addr + 8) = pb;
    __syncthreads();
  }
}

// ---------------- final projection: depth-2 triple-buffered counted-vmcnt pipeline ----------------
__global__ __launch_bounds__(256) void k_wo(
    const unsigned short* __restrict__ out1, const unsigned short* __restrict__ wo,
    const float* __restrict__ bo, float* __restrict__ dout)
{
  __shared__ __align__(16) unsigned short smem[3][6144];   // 3 x 12 KB: A blocks 0-3, B blocks 4-11
  const int nt = blockIdx.x;
  const int mt = blockIdx.y;
  const int w = threadIdx.x >> 6, lane = threadIdx.x & 63;
  const int wr = w >> 1, wc = w & 1;
  const int p = lane & 15, g = lane >> 4;
  const int m0 = mt*64, n0 = nt*128;
  const f4 fz = {0.f,0.f,0.f,0.f};
  f4 acc[2][4];
#pragma unroll
  for (int m=0;m<2;++m)
#pragma unroll
    for (int n=0;n<4;++n) acc[m][n] = fz;

  const int j0 = w*2, j1 = w*2 + 1;
  const unsigned short* gA = out1 + (size_t)(m0 + p)*1024 + g*8;
  const unsigned short* gB = wo   + (size_t)(n0 + p)*1024 + g*8;

#pragma unroll
  for (int t0=0; t0<2; ++t0){
    unsigned short* d0 = &smem[t0][0];
    const int kk = t0*32;
    gload16(gA + (size_t)w*16384 + kk, d0 + w*512);
    gload16(gB + (size_t)j0*16384 + kk, d0 + 2048 + j0*512);
    gload16(gB + (size_t)j1*16384 + kk, d0 + 2048 + j1*512);
  }

  int cur = 0, nxt2 = 2;
  for (int it=0; it<32; ++it){
    if (it < 30){
      const int kn = (it+2)*32;
      unsigned short* dn = &smem[nxt2][0];
      gload16(gA + (size_t)w*16384 + kn, dn + w*512);
      gload16(gB + (size_t)j0*16384 + kn, dn + 2048 + j0*512);
      gload16(gB + (size_t)j1*16384 + kn, dn + 2048 + j1*512);
      asm volatile("s_waitcnt vmcnt(6)" ::: "memory");
    } else if (it == 30){
      asm volatile("s_waitcnt vmcnt(3)" ::: "memory");
    } else {
      asm volatile("s_waitcnt vmcnt(0)" ::: "memory");
    }
    __builtin_amdgcn_sched_barrier(0);
    __builtin_amdgcn_s_barrier();
    __builtin_amdgcn_sched_barrier(0);
    {
      const unsigned short* Ab = &smem[cur][0];
      bfx8 af[2], bfr[4];
#pragma unroll
      for (int m=0;m<2;++m) af[m] = *(const bfx8*)(Ab + (wr*2+m)*512 + lane*8);
#pragma unroll
      for (int n=0;n<4;++n) bfr[n] = *(const bfx8*)(Ab + 2048 + (wc*4+n)*512 + lane*8);
#pragma unroll
      for (int m=0;m<2;++m)
#pragma unroll
        for (int n=0;n<4;++n)
          acc[m][n] = mfma32(af[m], bfr[n], acc[m][n]);
    }
    __builtin_amdgcn_sched_barrier(0);
    __builtin_amdgcn_s_barrier();
    __builtin_amdgcn_sched_barrier(0);
    cur = (cur == 2) ? 0 : cur + 1;
    nxt2 = (nxt2 == 2) ? 0 : nxt2 + 1;
  }

#pragma unroll
  for (int n=0;n<4;++n){
    const int col = n0 + wc*64 + n*16 + p;
    const float bias = bo[col];
#pragma unroll
    for (int m=0;m<2;++m)
#pragma unroll
      for (int r=0;r<4;++r){
        int row = m0 + wr*32 + m*16 + 4*g + r;
        int bb = row >> 10, s = row & 1023;
        dout[((size_t)s*4 + bb)*1024 + col] = acc[m][n][r] + bias;
      }
  }
}

extern "C" void kernel_launch(void* const* d_in, const int* in_sizes, int n_in,
                              void* d_out, int out_size, void* d_ws, size_t ws_size,
                              hipStream_t stream){
  const float* x   = (const float*)d_in[0];
  const float* wq  = (const float*)d_in[1];
  const float* wk  = (const float*)d_in[2];
  const float* wv  = (const float*)d_in[3];
  const float* wo  = (const float*)d_in[4];
  const float* bo  = (const float*)d_in[5];
  const float* rlk = (const float*)d_in[6];
  const float* rlv = (const float*)d_in[7];
  char* ws = (char*)d_ws;

  unsigned short* x_bf    = (unsigned short*)(ws + 0);
  unsigned short* wq_bf   = (unsigned short*)(ws + 8388608);   // [wq|wk|wv|wo] contiguous
  unsigned short* relk_bf = (unsigned short*)(ws + 16777216);
  unsigned short* relvT_bf= (unsigned short*)(ws + 16812032);
  unsigned short* Qf      = (unsigned short*)(ws + 16848896);   // fragment layout
  unsigned short* Kf      = (unsigned short*)(ws + 25237504);   // fragment layout
  unsigned short* Vf      = (unsigned short*)(ws + 33626112);   // fragment layout
  unsigned short* Qr2     = (unsigned short*)(ws + 42014720);   // 35.65 MB -> 77666304
  unsigned short* out1    = (unsigned short*)(ws + 113317888);  // 8 MB
  float*          ivf     = (float*)        (ws + 121706496);  // 16 MB -> 138483712
  unsigned short* wo_bf   = (unsigned short*)(ws + 14680064);

  k_prep<<<8264, 256, 0, stream>>>(x, wq, wk, wv, wo, rlk, rlv,
                                   x_bf, wq_bf, relk_bf, relvT_bf);

  k_qkv<<<dim3(24,4,8), 256, 0, stream>>>(x_bf, wq_bf, Qf, Kf, Vf);
  k_qr<<<512, 256, 0, stream>>>(Qf, relk_bf, Qr2);

  k_s   <<<2048, 512, 0, stream>>>(Qf, Kf, Qr2, ivf);
  k_attn<<<512, 256, 0, stream>>>(Qf, Kf, Vf, Qr2, ivf, relvT_bf, rlv, out1);
  k_wo<<<dim3(8,64), 256, 0, stream>>>(out1, wo_bf, bo, (float*)d_out);
}

// Round 23
// 217.422 us; speedup vs baseline: 1.0051x; 1.0002x over previous
//
#include <hip/hip_runtime.h>
#include <stdint.h>

#define DI __device__ __forceinline__

typedef __attribute__((ext_vector_type(8))) short bfx8;
typedef __attribute__((ext_vector_type(4))) short bfx4;
typedef __attribute__((ext_vector_type(4))) float f4;

DI unsigned short f2bf(float x){
  unsigned u = __float_as_uint(x);
  u = (u + 0x7FFFu + ((u >> 16) & 1u)) >> 16;
  return (unsigned short)u;
}
DI float bf2f(unsigned short h){ return __uint_as_float(((unsigned)h) << 16); }

// packed RNE f32->bf16x2 (same rounding as f2bf)
DI unsigned cvtpk(float lo, float hi){
  unsigned r;
  asm("v_cvt_pk_bf16_f32 %0, %1, %2" : "=v"(r) : "v"(lo), "v"(hi));
  return r;
}

DI f4 mfma32(bfx8 a, bfx8 b, f4 c){
  return __builtin_amdgcn_mfma_f32_16x16x32_bf16(a, b, c, 0, 0, 0);
}
#if __has_builtin(__builtin_amdgcn_mfma_f32_16x16x16bf16_1k)
DI f4 mfma16(bfx4 a, bfx4 b, f4 c){
  return __builtin_amdgcn_mfma_f32_16x16x16bf16_1k(a, b, c, 0, 0, 0);
}
#else
DI f4 mfma16(bfx4 a, bfx4 b, f4 c){
  f4 d = c;
  asm volatile("v_mfma_f32_16x16x16_bf16 %0, %1, %2, %0" : "+v"(d) : "v"(a), "v"(b));
  return d;
}
#endif

DI bfx4 lo4(bfx8 v){ bfx4 r; r[0]=v[0]; r[1]=v[1]; r[2]=v[2]; r[3]=v[3]; return r; }
DI bfx4 hi4(bfx8 v){ bfx4 r; r[0]=v[4]; r[1]=v[5]; r[2]=v[6]; r[3]=v[7]; return r; }

// async global->LDS, 16B per lane; LDS dest = wave-uniform base + lane*16
DI void gload16(const void* g, void* l){
  __builtin_amdgcn_global_load_lds(
      (__attribute__((address_space(1))) void*)g,
      (__attribute__((address_space(3))) void*)l, 16, 0, 0);
}

// Fragment layouts (all 16-bit elems):
//   Qf/Kf[bh][tile][lane][16]: elem[kf*8+j] = M[tile*16 + (lane&15)][kf*32 + 8*(lane>>4) + j]
//   Vf  [bh][tile][lane][16]: elem[df*4+j] = V[tile*16 + 4*(lane>>4) + j][df*16 + (lane&15)]
//   ivf [b][tt][st][lane][4]: elem[r] = 1/S at (s = st*16 + (lane&15), t = tt*16 + 4*(lane>>4) + r)

// ---------------- merged prep: x cast | 4 weight casts | rel tables ----------------
__global__ void k_prep(const float* __restrict__ x,
                       const float* __restrict__ wq, const float* __restrict__ wk,
                       const float* __restrict__ wv, const float* __restrict__ wo,
                       const float* __restrict__ rlk, const float* __restrict__ rlv,
                       unsigned short* __restrict__ x_bf, unsigned short* __restrict__ w_bf,
                       unsigned short* __restrict__ relk_bf, unsigned short* __restrict__ relvT_bf){
  const int bid = blockIdx.x;
  if (bid < 4096){
    int i = bid*256 + threadIdx.x;
    const float4 v = ((const float4*)x)[i];
    bfx4 o;
    o[0] = (short)f2bf(v.x); o[1] = (short)f2bf(v.y);
    o[2] = (short)f2bf(v.z); o[3] = (short)f2bf(v.w);
    *(bfx4*)(x_bf + (size_t)i*4) = o;
  } else if (bid < 8192){
    const int wb = (bid - 4096) >> 10;
    const float* src = (wb==0) ? wq : (wb==1) ? wk : (wb==2) ? wv : wo;
    int i = ((bid - 4096) & 1023)*256 + threadIdx.x;
    const float4 v = ((const float4*)src)[i];
    bfx4 o;
    o[0] = (short)f2bf(v.x); o[1] = (short)f2bf(v.y);
    o[2] = (short)f2bf(v.z); o[3] = (short)f2bf(v.w);
    *(bfx4*)(w_bf + (size_t)wb*1048576 + (size_t)i*4) = o;
  } else {
    int i = (bid - 8192)*256 + threadIdx.x;
    if (i < 272*64){
      int r = i >> 6, d = i & 63;
      relk_bf[i] = (r < 257) ? f2bf(rlk[r*64 + d]) : (unsigned short)0;
    }
    if (i < 64*288){
      int d = i / 288, r = i % 288;
      relvT_bf[i] = (r < 257) ? f2bf(rlv[(size_t)r*64 + d]) : (unsigned short)0;
    }
  }
}

// ---------------- QKV projections: depth-2 triple-buffered counted-vmcnt pipeline ----------------
__global__ __launch_bounds__(256, 3) void k_qkv(
    const unsigned short* __restrict__ xbf, const unsigned short* __restrict__ wqkv,
    unsigned short* __restrict__ Qf, unsigned short* __restrict__ Kf,
    unsigned short* __restrict__ Vf)
{
  __shared__ __align__(16) unsigned short smem[3][8192];   // 3 x 16 KB: A blocks 0-7, B blocks 8-15
  const int nt = blockIdx.x;
  const int b  = blockIdx.y;
  const int st = blockIdx.z;
  const int w = threadIdx.x >> 6, lane = threadIdx.x & 63;
  const int wr = w >> 1, wc = w & 1;
  const int p = lane & 15, g = lane >> 4;
  const int s0 = st*128;
  const int n0 = nt*128;
  const f4 fz = {0.f,0.f,0.f,0.f};
  f4 acc[4][4];
#pragma unroll
  for (int m=0;m<4;++m)
#pragma unroll
    for (int n=0;n<4;++n) acc[m][n] = fz;

  const int j0 = w*2, j1 = w*2 + 1;
  const unsigned short* gA = xbf  + (size_t)((s0 + p)*4 + b)*1024 + g*8;
  const unsigned short* gB = wqkv + (size_t)(n0 + p)*1024 + g*8;

  // prologue: stage tiles 0 and 1
#pragma unroll
  for (int t0=0; t0<2; ++t0){
    unsigned short* d0 = &smem[t0][0];
    const int kk = t0*32;
    gload16(gA + (size_t)j0*65536 + kk, d0 + j0*512);
    gload16(gA + (size_t)j1*65536 + kk, d0 + j1*512);
    gload16(gB + (size_t)j0*16384 + kk, d0 + 4096 + j0*512);
    gload16(gB + (size_t)j1*16384 + kk, d0 + 4096 + j1*512);
  }

  int cur = 0, nxt2 = 2;
  for (int it=0; it<32; ++it){
    if (it < 30){
      const int kn = (it+2)*32;
      unsigned short* dn = &smem[nxt2][0];
      gload16(gA + (size_t)j0*65536 + kn, dn + j0*512);
      gload16(gA + (size_t)j1*65536 + kn, dn + j1*512);
      gload16(gB + (size_t)j0*16384 + kn, dn + 4096 + j0*512);
      gload16(gB + (size_t)j1*16384 + kn, dn + 4096 + j1*512);
      asm volatile("s_waitcnt vmcnt(8)" ::: "memory");   // cur done; 2 tiles in flight
    } else if (it == 30){
      asm volatile("s_waitcnt vmcnt(4)" ::: "memory");
    } else {
      asm volatile("s_waitcnt vmcnt(0)" ::: "memory");
    }
    __builtin_amdgcn_sched_barrier(0);
    __builtin_amdgcn_s_barrier();
    __builtin_amdgcn_sched_barrier(0);
    {
      const unsigned short* Ab = &smem[cur][0];
      bfx8 af[4], bfr[4];
#pragma unroll
      for (int m=0;m<4;++m) af[m] = *(const bfx8*)(Ab + (wr*4+m)*512 + lane*8);
#pragma unroll
      for (int n=0;n<4;++n) bfr[n] = *(const bfx8*)(Ab + 4096 + (wc*4+n)*512 + lane*8);
#pragma unroll
      for (int m=0;m<4;++m)
#pragma unroll
        for (int n=0;n<4;++n)
          acc[m][n] = mfma32(af[m], bfr[n], acc[m][n]);
    }
    __builtin_amdgcn_sched_barrier(0);
    __builtin_amdgcn_s_barrier();
    __builtin_amdgcn_sched_barrier(0);
    cur = (cur == 2) ? 0 : cur + 1;
    nxt2 = (nxt2 == 2) ? 0 : nxt2 + 1;
  }

  const int n64 = n0 + wc*64;
  const int sec = n64 >> 10;            // 0 Q, 1 K, 2 V
  const int h = (n64 & 1023) >> 6;
  float* es = (float*)&smem[0][0] + w*1280;

  if (sec < 2){
    const float scl = (sec == 0) ? 0.125f : 1.0f;
    unsigned short* dst = (sec == 0) ? Qf : Kf;
#pragma unroll
    for (int m=0;m<4;++m){
#pragma unroll
      for (int n=0;n<4;++n)
#pragma unroll
        for (int r=0;r<4;++r)
          es[(4*g + r)*80 + 16*n + p] = acc[m][n][r] * scl;
      __syncthreads();
      f4 v0 = *(const f4*)&es[p*80 + 8*g];
      f4 v1 = *(const f4*)&es[p*80 + 8*g + 4];
      f4 v2 = *(const f4*)&es[p*80 + 32 + 8*g];
      f4 v3 = *(const f4*)&es[p*80 + 32 + 8*g + 4];
      bfx8 lo, hi;
#pragma unroll
      for (int j=0;j<4;++j){
        lo[j]   = (short)f2bf(v0[j]);
        lo[j+4] = (short)f2bf(v1[j]);
        hi[j]   = (short)f2bf(v2[j]);
        hi[j+4] = (short)f2bf(v3[j]);
      }
      size_t fb = ((size_t)(b*16 + h)*64 + (st*8 + wr*4 + m))*1024 + (size_t)lane*16;
      *(bfx8*)(dst + fb) = lo;
      *(bfx8*)(dst + fb + 8) = hi;
      __syncthreads();
    }
  } else {
#pragma unroll
    for (int m=0;m<4;++m){
#pragma unroll
      for (int n=0;n<4;++n)
        *(f4*)&es[(16*n + p)*20 + 4*g] = acc[m][n];
      __syncthreads();
      f4 vv0 = *(const f4*)&es[(p)*20 + 4*g];
      f4 vv1 = *(const f4*)&es[(16 + p)*20 + 4*g];
      f4 vv2 = *(const f4*)&es[(32 + p)*20 + 4*g];
      f4 vv3 = *(const f4*)&es[(48 + p)*20 + 4*g];
      bfx8 lo, hi;
#pragma unroll
      for (int j=0;j<4;++j){
        lo[j]   = (short)f2bf(vv0[j]);
        lo[j+4] = (short)f2bf(vv1[j]);
        hi[j]   = (short)f2bf(vv2[j]);
        hi[j+4] = (short)f2bf(vv3[j]);
      }
      size_t fb = ((size_t)(b*16 + h)*64 + (st*8 + wr*4 + m))*1024 + (size_t)lane*16;
      *(bfx8*)(Vf + fb) = lo;
      *(bfx8*)(Vf + fb + 8) = hi;
      __syncthreads();
    }
  }
}

// ---------------- Qr2 producer, write-coalesced: all 16 heads per block ----------------
__global__ __launch_bounds__(256) void k_qr(
    const unsigned short* __restrict__ Qf, const unsigned short* __restrict__ relk,
    unsigned short* __restrict__ Qr2)
{
  __shared__ __align__(16) unsigned short sst[16][16][24];
  const int bx = blockIdx.x;
  const int b  = bx & 3;
  const int st = (bx >> 2) & 63;
  const int uh = bx >> 8;
  const int w = threadIdx.x >> 6, lane = threadIdx.x & 63;
  const int p = lane & 15, g = lane >> 4;
  const int s0 = st << 4;
  const f4 fz = {0.f,0.f,0.f,0.f};

  bfx8 a0[4], a1[4];
#pragma unroll
  for (int hh=0; hh<4; ++hh){
    size_t fb = (((size_t)(b*16 + w*4 + hh))*64 + st)*1024 + (size_t)lane*16;
    a0[hh] = *(const bfx8*)(Qf + fb);
    a1[hh] = *(const bfx8*)(Qf + fb + 8);
  }

  const int c0 = uh ? 9 : 0;
  const int c1 = uh ? 17 : 9;
  const int so = threadIdx.x >> 4, uo = threadIdx.x & 15;

  for (int c=c0; c<c1; ++c){
    const int r0 = c << 4;
    bfx8 b0 = *(const bfx8*)(relk + (size_t)(r0 + p)*64 + 8*g);
    bfx8 b1 = *(const bfx8*)(relk + (size_t)(r0 + p)*64 + 32 + 8*g);
#pragma unroll
    for (int hh=0; hh<4; ++hh){
      f4 acc = mfma32(a1[hh], b1, mfma32(a0[hh], b0, fz));
#pragma unroll
      for (int r=0; r<4; ++r)
        sst[4*g + r][p][w*4 + hh] = f2bf(acc[r]);
    }
    __syncthreads();
    bfx8 v0 = *(const bfx8*)&sst[so][uo][0];
    bfx8 v1 = *(const bfx8*)&sst[so][uo][8];
    size_t ga = (((size_t)b*1024 + s0 + so)*272 + r0 + uo)*16;
    *(bfx8*)(Qr2 + ga) = v0;
    *(bfx8*)(Qr2 + ga + 8) = v1;
    __syncthreads();
  }
}

// ---------------- softmax denominator -> ivf; LDS-staged Q/K shared across 8 waves ----------------
__global__ __launch_bounds__(512, 4) void k_s(
    const unsigned short* __restrict__ Qf, const unsigned short* __restrict__ Kf,
    const unsigned short* __restrict__ Qr2, float* __restrict__ ivf)
{
  __shared__ __align__(16) unsigned short qs[2][2][1024];
  __shared__ __align__(16) unsigned short ks[2][4][1024];
  const int pbid = blockIdx.x;            // (stg<<6)|(ttg<<2)|b
  const int b   = pbid & 3;
  const int ttg = (pbid >> 2) & 15;
  const int stg = pbid >> 6;              // 0..31
  const int w = threadIdx.x >> 6, lane = threadIdx.x & 63;
  const int stl = w >> 2, ttl = w & 3;
  const int st = stg*2 + stl;
  const int tt = ttg*4 + ttl;
  const int p = lane & 15, g = lane >> 4;
  const int s = (st << 4) + p;
  const int t0 = tt << 4;
  const f4 fz = {0.f,0.f,0.f,0.f};

  bfx8 rv[4][2];
#pragma unroll
  for (int r=0; r<4; ++r){
    int t = t0 + 4*g + r;
    int u = s - t + 128; u = u < 0 ? 0 : (u > 256 ? 256 : u);
    const unsigned short* q = Qr2 + (((size_t)b*1024 + s)*272 + u)*16;
    rv[r][0] = *(const bfx8*)q;
    rv[r][1] = *(const bfx8*)(q + 8);
  }

  const bool stager = (w <= 1) || (w >= 4);
  const unsigned short* gsrc =
      (w <= 1) ? (Qf + ((size_t)(b*16)*64 + (stg*2 + w))*1024)
               : (Kf + ((size_t)(b*16)*64 + (ttg*4 + (w & 3)))*1024);
  unsigned short* ldst[2];
  ldst[0] = (w <= 1) ? &qs[0][w][0] : &ks[0][w & 3][0];
  ldst[1] = (w <= 1) ? &qs[1][w][0] : &ks[1][w & 3][0];

  if (stager){
    gload16(gsrc + (size_t)lane*8, ldst[0]);
    gload16(gsrc + 512 + (size_t)lane*8, ldst[0] + 512);
    asm volatile("s_waitcnt vmcnt(0)" ::: "memory");
  }
  __builtin_amdgcn_sched_barrier(0);
  __builtin_amdgcn_s_barrier();
  __builtin_amdgcn_sched_barrier(0);

  f4 ps = fz;
#pragma unroll
  for (int h=0; h<16; ++h){
    const int buf = h & 1;
    if (h < 15 && stager){
      unsigned short* ld = ldst[buf ^ 1];
      gload16(gsrc + (size_t)(h+1)*65536 + (size_t)lane*8, ld);
      gload16(gsrc + (size_t)(h+1)*65536 + 512 + (size_t)lane*8, ld + 512);
    }
    {
      const unsigned short* qb = &qs[buf][stl][lane*16];
      const unsigned short* kb = &ks[buf][ttl][lane*16];
      bfx8 q0 = *(const bfx8*)qb;
      bfx8 q1 = *(const bfx8*)(qb + 8);
      bfx8 k0 = *(const bfx8*)kb;
      bfx8 k1 = *(const bfx8*)(kb + 8);
      f4 sc = mfma32(k1, q1, mfma32(k0, q0, fz));
      const int hg = h >> 3, hr = h & 7;
#pragma unroll
      for (int r=0; r<4; ++r)
        ps[r] += __expf(sc[r] + bf2f((unsigned short)rv[r][hg][hr]));
    }
    if (h < 15){
      if (stager) asm volatile("s_waitcnt vmcnt(0)" ::: "memory");
      __builtin_amdgcn_sched_barrier(0);
      __builtin_amdgcn_s_barrier();
      __builtin_amdgcn_sched_barrier(0);
    }
  }

  f4 inv;
#pragma unroll
  for (int r=0; r<4; ++r) inv[r] = 1.0f / ps[r];
  *(f4*)(ivf + (((size_t)(b*64 + tt)*64 + st)*64 + lane)*4) = inv;
}

// ---------------- fused attention: ALL 64 t-tiles; 4 waves x 2 heads; unroll-2 set rotation ----------------
__global__ __launch_bounds__(256, 2) void k_attn(
    const unsigned short* __restrict__ Qf, const unsigned short* __restrict__ Kf,
    const unsigned short* __restrict__ Vf, const unsigned short* __restrict__ Qr2,
    const float* __restrict__ ivf, const unsigned short* __restrict__ relvT,
    const float* __restrict__ relv, unsigned short* __restrict__ out1)
{
  __shared__ __align__(16) unsigned short skew[128*264];   // 67,584 B
  const int pbid = blockIdx.x;
  const int xcd = pbid & 7;
  const int b = xcd >> 1;
  const int hhalf = (pbid >> 3) & 1;
  const int st = ((pbid >> 4) << 1) | (xcd & 1);
  const int s0 = st << 4;
  const int w = threadIdx.x >> 6;
  const int lane = threadIdx.x & 63;
  const int p = lane & 15, g = lane >> 4;
  const int s = s0 + p;
  const int hl0 = w * 2;                 // local head base (skew rows)
  const int h0 = hhalf*8 + hl0;          // global head base (memory)
  const f4 fz = {0.f,0.f,0.f,0.f};

  {
    unsigned* zp = (unsigned*)skew + w*4224;
    for (int i = lane; i < 4224; i += 64) zp[i] = 0u;
  }

  bfx8 qf[2][2]; float qr0[2], qr1[2];
#pragma unroll
  for (int hh=0; hh<2; ++hh){
    size_t qb = (((size_t)(b*16 + h0 + hh))*64 + st)*1024 + (size_t)lane*16;
    qf[hh][0] = *(const bfx8*)(Qf + qb);
    qf[hh][1] = *(const bfx8*)(Qf + qb + 8);
    qr0[hh] = bf2f(Qr2[(((size_t)b*1024 + s)*272 + 0)*16 + (h0+hh)]);
    qr1[hh] = bf2f(Qr2[(((size_t)b*1024 + s)*272 + 256)*16 + (h0+hh)]);
  }

  f4 o[2][4];
#pragma unroll
  for (int hh=0; hh<2; ++hh)
#pragma unroll
    for (int df=0; df<4; ++df) o[hh][df] = fz;

  float tl0[2] = {0.f,0.f};
  float tl1[2] = {0.f,0.f};

  const int tlo = (st-8 < 0) ? 0 : st-8;
  const int thi = (st+8 > 63) ? 63 : st+8;

  // double register sets, rotated by compile-time index (no v_mov rotation)
  bfx8 kc[2][2][2]; bfx8 vc8[2][2][2]; unsigned short qc[2][2][4]; f4 is[2];

  // prologue: prefetch tile 0 into set 0
#pragma unroll
  for (int hh=0; hh<2; ++hh){
    size_t bh = (size_t)(b*16 + h0 + hh);
    size_t fb = (bh*64 + 0)*1024 + (size_t)lane*16;
    kc[0][hh][0] = *(const bfx8*)(Kf + fb);
    kc[0][hh][1] = *(const bfx8*)(Kf + fb + 8);
    vc8[0][hh][0] = *(const bfx8*)(Vf + fb);
    vc8[0][hh][1] = *(const bfx8*)(Vf + fb + 8);
  }
  if (0 >= tlo){     // tile 0 in near band (st<=8)
#pragma unroll
    for (int hh=0; hh<2; ++hh)
#pragma unroll
      for (int r=0; r<4; ++r){
        int t = 4*g + r;
        int u = s - t + 128; u = u < 0 ? 0 : (u > 256 ? 256 : u);
        qc[0][hh][r] = Qr2[(((size_t)b*1024 + s)*272 + u)*16 + (h0+hh)];
      }
  }
  is[0] = *(const f4*)(ivf + (((size_t)(b*64 + 0)*64 + st)*64 + lane)*4);

  for (int tb = 0; tb < 32; ++tb){
#pragma unroll
    for (int sub = 0; sub < 2; ++sub){
      const int cur = sub, nxt = sub ^ 1;
      const int ti = tb*2 + sub;
      const int t0 = ti << 4;
      const bool nearT = (ti >= tlo) && (ti <= thi);

      if (ti < 63){
        const int tn = ti + 1;
#pragma unroll
        for (int hh=0; hh<2; ++hh){
          size_t bh = (size_t)(b*16 + h0 + hh);
          size_t fb = (bh*64 + tn)*1024 + (size_t)lane*16;
          kc[nxt][hh][0] = *(const bfx8*)(Kf + fb);
          kc[nxt][hh][1] = *(const bfx8*)(Kf + fb + 8);
          vc8[nxt][hh][0] = *(const bfx8*)(Vf + fb);
          vc8[nxt][hh][1] = *(const bfx8*)(Vf + fb + 8);
        }
        if (tn >= tlo && tn <= thi){
#pragma unroll
          for (int hh=0; hh<2; ++hh)
#pragma unroll
            for (int r=0; r<4; ++r){
              int t = (tn<<4) + 4*g + r;
              int u = s - t + 128; u = u < 0 ? 0 : (u > 256 ? 256 : u);
              qc[nxt][hh][r] = Qr2[(((size_t)b*1024 + s)*272 + u)*16 + (h0+hh)];
            }
        }
        is[nxt] = *(const f4*)(ivf + (((size_t)(b*64 + tn)*64 + st)*64 + lane)*4);
      }

      if (nearT){
#pragma unroll
        for (int hh=0; hh<2; ++hh){
          f4 sc = mfma32(kc[cur][hh][1], qf[hh][1], mfma32(kc[cur][hh][0], qf[hh][0], fz));
          f4 at;
#pragma unroll
          for (int r=0; r<4; ++r) at[r] = __expf(sc[r] + bf2f(qc[cur][hh][r])) * is[cur][r];
          const unsigned w0 = cvtpk(at[0], at[1]);
          const unsigned w1 = cvtpk(at[2], at[3]);
          const unsigned short abf[4] = {
            (unsigned short)(w0 & 0xffffu), (unsigned short)(w0 >> 16),
            (unsigned short)(w1 & 0xffffu), (unsigned short)(w1 >> 16) };
          const int row = (hl0 + hh)*16 + p;
#pragma unroll
          for (int r=0; r<4; ++r){
            int t = t0 + 4*g + r;
            int u = s - t + 128;
            if (u <= 0) tl0[hh] += at[r];
            else if (u >= 256) tl1[hh] += at[r];
            else skew[row*264 + u] = abf[r];
          }
          union { unsigned u[2]; bfx4 v; } cv;
          cv.u[0] = w0; cv.u[1] = w1;
          const bfx4 pk = cv.v;
          o[hh][0] = mfma16(lo4(vc8[cur][hh][0]), pk, o[hh][0]);
          o[hh][1] = mfma16(hi4(vc8[cur][hh][0]), pk, o[hh][1]);
          o[hh][2] = mfma16(lo4(vc8[cur][hh][1]), pk, o[hh][2]);
          o[hh][3] = mfma16(hi4(vc8[cur][hh][1]), pk, o[hh][3]);
        }
      } else {
        const bool hiSide = (ti < st);     // u >= 256 side
#pragma unroll
        for (int hh=0; hh<2; ++hh){
          f4 sc = mfma32(kc[cur][hh][1], qf[hh][1], mfma32(kc[cur][hh][0], qf[hh][0], fz));
          const float qa = hiSide ? qr1[hh] : qr0[hh];
          f4 at;
#pragma unroll
          for (int r=0; r<4; ++r) at[r] = __expf(sc[r] + qa) * is[cur][r];
          float tsum = at[0] + at[1] + at[2] + at[3];
          if (hiSide) tl1[hh] += tsum; else tl0[hh] += tsum;
          const unsigned w0 = cvtpk(at[0], at[1]);
          const unsigned w1 = cvtpk(at[2], at[3]);
          union { unsigned u[2]; bfx4 v; } cv;
          cv.u[0] = w0; cv.u[1] = w1;
          const bfx4 pk = cv.v;
          o[hh][0] = mfma16(lo4(vc8[cur][hh][0]), pk, o[hh][0]);
          o[hh][1] = mfma16(hi4(vc8[cur][hh][0]), pk, o[hh][1]);
          o[hh][2] = mfma16(lo4(vc8[cur][hh][1]), pk, o[hh][2]);
          o[hh][3] = mfma16(hi4(vc8[cur][hh][1]), pk, o[hh][3]);
        }
      }
    }
  }

  __syncthreads();

  // ---- fused out2 = rel_v^T @ skew (own-wave rows only; local head rows) ----
  f4 acc2[2][4];
#pragma unroll
  for (int hh=0; hh<2; ++hh)
#pragma unroll
    for (int df=0; df<4; ++df) acc2[hh][df] = fz;
#pragma unroll
  for (int k0=0; k0<256; k0+=32){
    bfx8 bb0 = *(const bfx8*)&skew[(hl0*16 + p)*264 + k0 + 8*g];
    bfx8 bb1 = *(const bfx8*)&skew[((hl0+1)*16 + p)*264 + k0 + 8*g];
#pragma unroll
    for (int df=0; df<4; ++df){
      bfx8 a = *(const bfx8*)(relvT + (size_t)(df*16 + p)*288 + k0 + 8*g);
      acc2[0][df] = mfma32(a, bb0, acc2[0][df]);
      acc2[1][df] = mfma32(a, bb1, acc2[1][df]);
    }
  }

  f4 rv0[4], rv1[4];
#pragma unroll
  for (int df=0; df<4; ++df){
    rv0[df] = *(const f4*)(relv + df*16 + 4*g);
    rv1[df] = *(const f4*)(relv + 16384 + df*16 + 4*g);
  }
#pragma unroll
  for (int hh=0; hh<2; ++hh){
    float tv0 = tl0[hh];
    tv0 += __shfl_xor(tv0, 16, 64);
    tv0 += __shfl_xor(tv0, 32, 64);
    float tv1 = tl1[hh];
    tv1 += __shfl_xor(tv1, 16, 64);
    tv1 += __shfl_xor(tv1, 32, 64);
#pragma unroll
    for (int df=0; df<4; ++df)
#pragma unroll
      for (int r=0; r<4; ++r)
        o[hh][df][r] += acc2[hh][df][r] + tv0*rv0[df][r] + tv1*rv1[df][r];
  }

  __syncthreads();

  float* slabBase = (float*)skew;
  float (*tb2)[68] = (float(*)[68])(slabBase + w*(16*68));
#pragma unroll
  for (int hh=0; hh<2; ++hh){
#pragma unroll
    for (int df=0; df<4; ++df)
      *(f4*)&tb2[p][df*16 + 4*g] = o[hh][df];
    __syncthreads();
    const int srow = lane >> 2, quad = lane & 3;
    f4 r0 = *(const f4*)&tb2[srow][quad*16 + 0];
    f4 r1 = *(const f4*)&tb2[srow][quad*16 + 4];
    f4 r2 = *(const f4*)&tb2[srow][quad*16 + 8];
    f4 r3 = *(const f4*)&tb2[srow][quad*16 + 12];
    size_t addr = ((size_t)b*1024 + s0 + srow)*1024 + (h0+hh)*64 + quad*16;
    bfx8 pa, pb;
#pragma unroll
    for (int j=0; j<4; ++j){
      pa[j]   = (short)f2bf(r0[j]);
      pa[j+4] = (short)f2bf(r1[j]);
      pb[j]   = (short)f2bf(r2[j]);
      pb[j+4] = (short)f2bf(r3[j]);
    }
    *(bfx8*)(out1 + addr) = pa;
    *(bfx8*)(out1 + addr + 8) = pb;
    __syncthreads();
  }
}

// ---------------- final projection: depth-2 triple-buffered counted-vmcnt pipeline ----------------
__global__ __launch_bounds__(256) void k_wo(
    const unsigned short* __restrict__ out1, const unsigned short* __restrict__ wo,
    const float* __restrict__ bo, float* __restrict__ dout)
{
  __shared__ __align__(16) unsigned short smem[3][6144];   // 3 x 12 KB: A blocks 0-3, B blocks 4-11
  const int nt = blockIdx.x;
  const int mt = blockIdx.y;
  const int w = threadIdx.x >> 6, lane = threadIdx.x & 63;
  const int wr = w >> 1, wc = w & 1;
  const int p = lane & 15, g = lane >> 4;
  const int m0 = mt*64, n0 = nt*128;
  const f4 fz = {0.f,0.f,0.f,0.f};
  f4 acc[2][4];
#pragma unroll
  for (int m=0;m<2;++m)
#pragma unroll
    for (int n=0;n<4;++n) acc[m][n] = fz;

  const int j0 = w*2, j1 = w*2 + 1;
  const unsigned short* gA = out1 + (size_t)(m0 + p)*1024 + g*8;
  const unsigned short* gB = wo   + (size_t)(n0 + p)*1024 + g*8;

#pragma unroll
  for (int t0=0; t0<2; ++t0){
    unsigned short* d0 = &smem[t0][0];
    const int kk = t0*32;
    gload16(gA + (size_t)w*16384 + kk, d0 + w*512);
    gload16(gB + (size_t)j0*16384 + kk, d0 + 2048 + j0*512);
    gload16(gB + (size_t)j1*16384 + kk, d0 + 2048 + j1*512);
  }

  int cur = 0, nxt2 = 2;
  for (int it=0; it<32; ++it){
    if (it < 30){
      const int kn = (it+2)*32;
      unsigned short* dn = &smem[nxt2][0];
      gload16(gA + (size_t)w*16384 + kn, dn + w*512);
      gload16(gB + (size_t)j0*16384 + kn, dn + 2048 + j0*512);
      gload16(gB + (size_t)j1*16384 + kn, dn + 2048 + j1*512);
      asm volatile("s_waitcnt vmcnt(6)" ::: "memory");
    } else if (it == 30){
      asm volatile("s_waitcnt vmcnt(3)" ::: "memory");
    } else {
      asm volatile("s_waitcnt vmcnt(0)" ::: "memory");
    }
    __builtin_amdgcn_sched_barrier(0);
    __builtin_amdgcn_s_barrier();
    __builtin_amdgcn_sched_barrier(0);
    {
      const unsigned short* Ab = &smem[cur][0];
      bfx8 af[2], bfr[4];
#pragma unroll
      for (int m=0;m<2;++m) af[m] = *(const bfx8*)(Ab + (wr*2+m)*512 + lane*8);
#pragma unroll
      for (int n=0;n<4;++n) bfr[n] = *(const bfx8*)(Ab + 2048 + (wc*4+n)*512 + lane*8);
#pragma unroll
      for (int m=0;m<2;++m)
#pragma unroll
        for (int n=0;n<4;++n)
          acc[m][n] = mfma32(af[m], bfr[n], acc[m][n]);
    }
    __builtin_amdgcn_sched_barrier(0);
    __builtin_amdgcn_s_barrier();
    __builtin_amdgcn_sched_barrier(0);
    cur = (cur == 2) ? 0 : cur + 1;
    nxt2 = (nxt2 == 2) ? 0 : nxt2 + 1;
  }

#pragma unroll
  for (int n=0;n<4;++n){
    const int col = n0 + wc*64 + n*16 + p;
    const float bias = bo[col];
#pragma unroll
    for (int m=0;m<2;++m)
#pragma unroll
      for (int r=0;r<4;++r){
        int row = m0 + wr*32 + m*16 + 4*g + r;
        int bb = row >> 10, s = row & 1023;
        dout[((size_t)s*4 + bb)*1024 + col] = acc[m][n][r] + bias;
      }
  }
}

extern "C" void kernel_launch(void* const* d_in, const int* in_sizes, int n_in,
                              void* d_out, int out_size, void* d_ws, size_t ws_size,
                              hipStream_t stream){
  const float* x   = (const float*)d_in[0];
  const float* wq  = (const float*)d_in[1];
  const float* wk  = (const float*)d_in[2];
  const float* wv  = (const float*)d_in[3];
  const float* wo  = (const float*)d_in[4];
  const float* bo  = (const float*)d_in[5];
  const float* rlk = (const float*)d_in[6];
  const float* rlv = (const float*)d_in[7];
  char* ws = (char*)d_ws;

  unsigned short* x_bf    = (unsigned short*)(ws + 0);
  unsigned short* wq_bf   = (unsigned short*)(ws + 8388608);   // [wq|wk|wv|wo] contiguous
  unsigned short* relk_bf = (unsigned short*)(ws + 16777216);
  unsigned short* relvT_bf= (unsigned short*)(ws + 16812032);
  unsigned short* Qf      = (unsigned short*)(ws + 16848896);   // fragment layout
  unsigned short* Kf      = (unsigned short*)(ws + 25237504);   // fragment layout
  unsigned short* Vf      = (unsigned short*)(ws + 33626112);   // fragment layout
  unsigned short* Qr2     = (unsigned short*)(ws + 42014720);   // 35.65 MB -> 77666304
  unsigned short* out1    = (unsigned short*)(ws + 113317888);  // 8 MB
  float*          ivf     = (float*)        (ws + 121706496);  // 16 MB -> 138483712
  unsigned short* wo_bf   = (unsigned short*)(ws + 14680064);

  k_prep<<<8264, 256, 0, stream>>>(x, wq, wk, wv, wo, rlk, rlv,
                                   x_bf, wq_bf, relk_bf, relvT_bf);

  k_qkv<<<dim3(24,4,8), 256, 0, stream>>>(x_bf, wq_bf, Qf, Kf, Vf);
  k_qr<<<512, 256, 0, stream>>>(Qf, relk_bf, Qr2);

  k_s   <<<2048, 512, 0, stream>>>(Qf, Kf, Qr2, ivf);
  k_attn<<<512, 256, 0, stream>>>(Qf, Kf, Vf, Qr2, ivf, relvT_bf, rlv, out1);
  k_wo<<<dim3(8,64), 256, 0, stream>>>(out1, wo_bf, bo, (float*)d_out);
}